// Round 9
// baseline (382.249 us; speedup 1.0000x reference)
//
#include <hip/hip_runtime.h>
#include <hip/hip_bf16.h>

#define B_SZ 4096
#define NHID_ 2048

typedef __bf16 bf16x8 __attribute__((ext_vector_type(8)));
typedef float f32x4 __attribute__((ext_vector_type(4)));
typedef float f32x16 __attribute__((ext_vector_type(16)));

__device__ __forceinline__ float sigmoidf_(float x) { return 1.f / (1.f + expf(-x)); }
__device__ __forceinline__ float b2f_(unsigned short u) {
    unsigned v = (unsigned)u << 16;
    return __builtin_bit_cast(float, v);
}

#define GLDS16(gp, lp) __builtin_amdgcn_global_load_lds( \
    (const __attribute__((address_space(1))) void*)(gp), \
    (__attribute__((address_space(3))) void*)(lp), 16, 0, 0)

// ---------------------------------------------------------------------------
// fp32 -> bf16 conversion, 4 elems/thread, grid-stride
// ---------------------------------------------------------------------------
__global__ __launch_bounds__(256) void f2b_kernel(
    const float* __restrict__ src, __hip_bfloat16* __restrict__ dst, long n4)
{
    long i = (long)blockIdx.x * 256 + threadIdx.x;
    const long stride = (long)gridDim.x * 256;
    for (; i < n4; i += stride) {
        float4 v = ((const float4*)src)[i];
        __hip_bfloat16 b0 = __float2bfloat16(v.x);
        __hip_bfloat16 b1 = __float2bfloat16(v.y);
        __hip_bfloat16 b2 = __float2bfloat16(v.z);
        __hip_bfloat16 b3 = __float2bfloat16(v.w);
        ushort4 u;
        u.x = *(unsigned short*)&b0; u.y = *(unsigned short*)&b1;
        u.z = *(unsigned short*)&b2; u.w = *(unsigned short*)&b3;
        ((ushort4*)dst)[i] = u;
    }
}

// ---------------------------------------------------------------------------
// Wih convert + cb: Wihb = bf16(Wih); cb[j] = dot(fc_i_b, Wih[j,:]) + bih[j]
// ---------------------------------------------------------------------------
__global__ __launch_bounds__(256) void wih_prep(
    const float* __restrict__ Wih, const float* __restrict__ fc_i_b,
    const float* __restrict__ bih, __hip_bfloat16* __restrict__ Wihb,
    float* __restrict__ cb)
{
    long j = blockIdx.x;
    const float* row = Wih + j * 1024;
    __hip_bfloat16* drow = Wihb + j * 1024;
    int i = threadIdx.x * 4;
    float4 v = *(const float4*)(row + i);
    __hip_bfloat16 b0 = __float2bfloat16(v.x);
    __hip_bfloat16 b1 = __float2bfloat16(v.y);
    __hip_bfloat16 b2 = __float2bfloat16(v.z);
    __hip_bfloat16 b3 = __float2bfloat16(v.w);
    ushort4 u;
    u.x = *(unsigned short*)&b0; u.y = *(unsigned short*)&b1;
    u.z = *(unsigned short*)&b2; u.w = *(unsigned short*)&b3;
    *(ushort4*)(drow + i) = u;
    float s = fc_i_b[i] * v.x + fc_i_b[i + 1] * v.y +
              fc_i_b[i + 2] * v.z + fc_i_b[i + 3] * v.w;
#pragma unroll
    for (int off = 32; off > 0; off >>= 1) s += __shfl_xor(s, off, 64);
    __shared__ float red[4];
    if ((threadIdx.x & 63) == 0) red[threadIdx.x >> 6] = s;
    __syncthreads();
    if (threadIdx.x == 0) cb[j] = red[0] + red[1] + red[2] + red[3] + bih[j];
}

// ---------------------------------------------------------------------------
// Transpose + convert: dst[c*ldd + r] (bf16) = src[r*C + c] (f32), batched z.
// ---------------------------------------------------------------------------
__global__ __launch_bounds__(256) void tconv_kernel(
    const float* __restrict__ src, int C, long sS,
    __hip_bfloat16* __restrict__ dst, int ldd, long sD)
{
    src += (long)blockIdx.z * sS;
    dst += (long)blockIdx.z * sD;
    const int r0 = blockIdx.y * 32, c0 = blockIdx.x * 32;
    const int tx = threadIdx.x & 31, ty = threadIdx.x >> 5;
    __shared__ float tile[32][33];
#pragma unroll
    for (int i = 0; i < 4; ++i)
        tile[ty + i * 8][tx] = src[(long)(r0 + ty + i * 8) * C + c0 + tx];
    __syncthreads();
#pragma unroll
    for (int i = 0; i < 4; ++i)
        dst[(long)(c0 + ty + i * 8) * ldd + r0 + tx] = __float2bfloat16(tile[tx][ty + i * 8]);
}

// ---------------------------------------------------------------------------
// Build fcgT (512 x 64)
// ---------------------------------------------------------------------------
__global__ __launch_bounds__(256) void fcg_prep(
    const float* __restrict__ fc_w, const float* __restrict__ gate_w,
    __hip_bfloat16* __restrict__ fcgT)
{
    int tid = blockIdx.x * 256 + threadIdx.x;  // 32768
    int np = tid >> 6, k = tid & 63;
    int o = (np >> 5) * 16 + (np & 15);
    const float* src = ((np >> 4) & 1) ? gate_w : fc_w;
    fcgT[tid] = __float2bfloat16(src[k * 256 + o]);
}

// ---------------------------------------------------------------------------
// Generic fp32 tiled GEMM (krow only)
// ---------------------------------------------------------------------------
#define GM_BM 64
#define GM_BN 64
#define GM_BK 16

__global__ __launch_bounds__(256) void gemm_nn(
    const float* __restrict__ A, const float* __restrict__ Bm, float* __restrict__ C,
    int M, int N, int K, int lda, int ldb, int ldc,
    long sA, long sB, long sC)
{
    const int z = blockIdx.z;
    A += (long)z * sA; Bm += (long)z * sB; C += (long)z * sC;
    const int m0 = blockIdx.y * GM_BM;
    const int n0 = blockIdx.x * GM_BN;
    const int tid = threadIdx.x;
    const int tx = tid & 15;
    const int ty = tid >> 4;

    __shared__ float As[GM_BK][GM_BM + 4];
    __shared__ float Bs[GM_BK][GM_BN + 4];

    float acc[4][4] = {};

    for (int k0 = 0; k0 < K; k0 += GM_BK) {
#pragma unroll
        for (int i = 0; i < 4; ++i) {
            int idx = tid + i * 256;
            int r = idx >> 4, c = idx & 15;
            As[c][r] = A[(long)(m0 + r) * lda + k0 + c];
        }
#pragma unroll
        for (int i = 0; i < 4; ++i) {
            int idx = tid + i * 256;
            int r = idx >> 6, c = idx & 63;
            Bs[r][c] = Bm[(long)(k0 + r) * ldb + n0 + c];
        }
        __syncthreads();
#pragma unroll
        for (int kk = 0; kk < GM_BK; ++kk) {
            float4 a4 = *(const float4*)&As[kk][ty * 4];
            float4 b4 = *(const float4*)&Bs[kk][tx * 4];
            float av[4] = {a4.x, a4.y, a4.z, a4.w};
            float bv[4] = {b4.x, b4.y, b4.z, b4.w};
#pragma unroll
            for (int i = 0; i < 4; ++i)
#pragma unroll
                for (int j = 0; j < 4; ++j)
                    acc[i][j] += av[i] * bv[j];
        }
        __syncthreads();
    }
#pragma unroll
    for (int i = 0; i < 4; ++i) {
        long m = m0 + ty * 4 + i;
#pragma unroll
        for (int j = 0; j < 4; ++j) {
            int n = n0 + tx * 4 + j;
            C[m * ldc + n] = acc[i][j];
        }
    }
}

// ---------------------------------------------------------------------------
// fp32 GEMM with N-major B: C(MxN) = A(MxK) @ BT(NxK)^T, batched z over BT/C.
// ---------------------------------------------------------------------------
__global__ __launch_bounds__(256) void gemm_nt_f32(
    const float* __restrict__ A, int lda,
    const float* __restrict__ BT, int ldb,
    float* __restrict__ C, int ldc, int K, long sB, long sC)
{
    BT += (long)blockIdx.z * sB;
    C  += (long)blockIdx.z * sC;
    const int m0 = blockIdx.y * 64;
    const int n0 = blockIdx.x * 64;
    const int tid = threadIdx.x;
    const int tx = tid & 15;
    const int ty = tid >> 4;

    __shared__ float As[16][68];
    __shared__ float Bs[64][17];

    float acc[4][4] = {};

    for (int k0 = 0; k0 < K; k0 += 16) {
#pragma unroll
        for (int i = 0; i < 4; ++i) {
            int idx = tid + i * 256;
            int r = idx >> 4, c = idx & 15;
            As[c][r] = A[(long)(m0 + r) * lda + k0 + c];
        }
#pragma unroll
        for (int i = 0; i < 4; ++i) {
            int idx = tid + i * 256;
            int r = idx >> 4, c = idx & 15;
            Bs[r][c] = BT[(long)(n0 + r) * ldb + k0 + c];
        }
        __syncthreads();
#pragma unroll
        for (int kk = 0; kk < 16; ++kk) {
            float4 a4 = *(const float4*)&As[kk][ty * 4];
            float av[4] = {a4.x, a4.y, a4.z, a4.w};
            float bv[4];
#pragma unroll
            for (int j = 0; j < 4; ++j) bv[j] = Bs[tx * 4 + j][kk];
#pragma unroll
            for (int i = 0; i < 4; ++i)
#pragma unroll
                for (int j = 0; j < 4; ++j)
                    acc[i][j] += av[i] * bv[j];
        }
        __syncthreads();
    }
#pragma unroll
    for (int i = 0; i < 4; ++i) {
        long m = m0 + ty * 4 + i;
#pragma unroll
        for (int j = 0; j < 4; ++j) {
            int n = n0 + tx * 4 + j;
            C[m * ldc + n] = acc[i][j];
        }
    }
}

// ---------------------------------------------------------------------------
// Fused s1 / sigmoid / top-k mask: s1[b,n] = (hx3[b,n,:] . p[b,n,:]) / 8.
// ---------------------------------------------------------------------------
__global__ __launch_bounds__(256) void s1_mask_fused(
    const float* __restrict__ hx,   // (B,2048)
    const float* __restrict__ p,    // (B,2048)  p[b, n*256+i]
    float* __restrict__ a_buf, float* __restrict__ mask_buf)
{
    const int wave = threadIdx.x >> 6;
    const int lane = threadIdx.x & 63;
    const long b = (long)blockIdx.x * 4 + wave;
    const long base = b * 2048 + lane * 4;
    float s1v[8];
#pragma unroll
    for (int n = 0; n < 8; ++n) {
        float4 hv = *(const float4*)(hx + base + n * 256);
        float4 pv = *(const float4*)(p + base + n * 256);
        float s = hv.x * pv.x + hv.y * pv.y + hv.z * pv.z + hv.w * pv.w;
#pragma unroll
        for (int off = 32; off > 0; off >>= 1) s += __shfl_xor(s, off, 64);
        s1v[n] = s * 0.125f;
    }
    unsigned maskbits = 0;
#pragma unroll
    for (int n = 0; n < 8; ++n) {
        int rank = 0;
#pragma unroll
        for (int m = 0; m < 8; ++m) {
            if (m == n) continue;
            if (s1v[m] < s1v[n] || (s1v[m] == s1v[n] && m < n)) rank++;
        }
        if (rank >= 4) maskbits |= (1u << n);
    }
    if (lane < 8) {
        float sv = s1v[0];
#pragma unroll
        for (int n = 1; n < 8; ++n)
            if (lane == n) sv = s1v[n];
        a_buf[b * 8 + lane] = sigmoidf_(sv);
        mask_buf[b * 8 + lane] = ((maskbits >> lane) & 1u) ? 1.0f : 0.0f;
    }
}

// ---------------------------------------------------------------------------
// MFMA GEMM: C(bf16, MxN) = A(bf16, MxK, lda) @ BT(bf16, NxK, ldb)^T
// ---------------------------------------------------------------------------
__global__ __launch_bounds__(256) void gemm_mfma_obf16(
    const __hip_bfloat16* __restrict__ A, int lda,
    const __hip_bfloat16* __restrict__ BT, int ldb,
    __hip_bfloat16* __restrict__ C, int ldc, int K)
{
    const int m0 = blockIdx.y * 128;
    const int n0 = blockIdx.x * 64;
    const int tid = threadIdx.x;
    const int lane = tid & 63, wid = tid >> 6;
    const int wr = wid >> 1, wc = wid & 1;
    const int l15 = lane & 15, l4 = lane >> 4;

    __shared__ __align__(16) char lds_raw[16384 + 8192];
    char* Alds = lds_raw;
    char* Blds = lds_raw + 16384;

    f32x4 acc[4][2] = {};

    for (int k0 = 0; k0 < K; k0 += 64) {
#pragma unroll
        for (int ii = 0; ii < 4; ++ii) {
            int issue = ii * 4 + wid;
            int chunk = issue * 64 + lane;
            int r = chunk >> 3, cs = chunk & 7;
            int cl = cs ^ (r & 7);
            const __hip_bfloat16* g = A + (long)(m0 + r) * lda + k0 + cl * 8;
            GLDS16(g, Alds + issue * 1024);
        }
#pragma unroll
        for (int jj = 0; jj < 2; ++jj) {
            int issue = jj * 4 + wid;
            int chunk = issue * 64 + lane;
            int r = chunk >> 3, cs = chunk & 7;
            int cl = cs ^ (r & 7);
            const __hip_bfloat16* g = BT + (long)(n0 + r) * ldb + k0 + cl * 8;
            GLDS16(g, Blds + issue * 1024);
        }
        __syncthreads();
#pragma unroll
        for (int kk = 0; kk < 2; ++kk) {
            bf16x8 af[4], bfr[2];
#pragma unroll
            for (int im = 0; im < 4; ++im) {
                int r = wr * 64 + im * 16 + l15;
                int cl = (kk * 4 + l4) ^ (l15 & 7);
                af[im] = *(const bf16x8*)(Alds + r * 128 + cl * 16);
            }
#pragma unroll
            for (int jn = 0; jn < 2; ++jn) {
                int r = wc * 32 + jn * 16 + l15;
                int cl = (kk * 4 + l4) ^ (l15 & 7);
                bfr[jn] = *(const bf16x8*)(Blds + r * 128 + cl * 16);
            }
#pragma unroll
            for (int im = 0; im < 4; ++im)
#pragma unroll
                for (int jn = 0; jn < 2; ++jn)
                    acc[im][jn] = __builtin_amdgcn_mfma_f32_16x16x32_bf16(
                        af[im], bfr[jn], acc[im][jn], 0, 0, 0);
        }
        __syncthreads();
    }
#pragma unroll
    for (int im = 0; im < 4; ++im)
#pragma unroll
        for (int reg = 0; reg < 4; ++reg) {
            long m = m0 + wr * 64 + im * 16 + l4 * 4 + reg;
#pragma unroll
            for (int jn = 0; jn < 2; ++jn) {
                int n = n0 + wc * 32 + jn * 16 + l15;
                C[m * ldc + n] = __float2bfloat16(acc[im][jn][reg]);
            }
        }
}

// ---------------------------------------------------------------------------
// Fused q/k/v_m projections (bf16 out).
// ---------------------------------------------------------------------------
__global__ __launch_bounds__(256) void gemm_mfma_qkv(
    const __hip_bfloat16* __restrict__ hnewb,  // (B,2048)
    const __hip_bfloat16* __restrict__ WmT,    // (8,192,256)
    __hip_bfloat16* __restrict__ qout)         // q|k|v, each 2097152 bf16
{
    const int z = blockIdx.z;
    const int m0 = blockIdx.y * 128;
    const int n0 = blockIdx.x * 64;
    const int tid = threadIdx.x;
    const int lane = tid & 63, wid = tid >> 6;
    const int wr = wid >> 1, wc = wid & 1;
    const int l15 = lane & 15, l4 = lane >> 4;

    const __hip_bfloat16* A = hnewb + z * 256;
    const __hip_bfloat16* BT = WmT + (long)z * 192 * 256;

    __shared__ __align__(16) char lds_raw[16384 + 8192];
    char* Alds = lds_raw;
    char* Blds = lds_raw + 16384;

    f32x4 acc[4][2] = {};

    for (int k0 = 0; k0 < 256; k0 += 64) {
#pragma unroll
        for (int ii = 0; ii < 4; ++ii) {
            int issue = ii * 4 + wid;
            int chunk = issue * 64 + lane;
            int r = chunk >> 3, cs = chunk & 7;
            int cl = cs ^ (r & 7);
            const __hip_bfloat16* g = A + (long)(m0 + r) * 2048 + k0 + cl * 8;
            GLDS16(g, Alds + issue * 1024);
        }
#pragma unroll
        for (int jj = 0; jj < 2; ++jj) {
            int issue = jj * 4 + wid;
            int chunk = issue * 64 + lane;
            int r = chunk >> 3, cs = chunk & 7;
            int cl = cs ^ (r & 7);
            const __hip_bfloat16* g = BT + (long)(n0 + r) * 256 + k0 + cl * 8;
            GLDS16(g, Blds + issue * 1024);
        }
        __syncthreads();
#pragma unroll
        for (int kk = 0; kk < 2; ++kk) {
            bf16x8 af[4], bfr[2];
#pragma unroll
            for (int im = 0; im < 4; ++im) {
                int r = wr * 64 + im * 16 + l15;
                int cl = (kk * 4 + l4) ^ (l15 & 7);
                af[im] = *(const bf16x8*)(Alds + r * 128 + cl * 16);
            }
#pragma unroll
            for (int jn = 0; jn < 2; ++jn) {
                int r = wc * 32 + jn * 16 + l15;
                int cl = (kk * 4 + l4) ^ (l15 & 7);
                bfr[jn] = *(const bf16x8*)(Blds + r * 128 + cl * 16);
            }
#pragma unroll
            for (int im = 0; im < 4; ++im)
#pragma unroll
                for (int jn = 0; jn < 2; ++jn)
                    acc[im][jn] = __builtin_amdgcn_mfma_f32_16x16x32_bf16(
                        af[im], bfr[jn], acc[im][jn], 0, 0, 0);
        }
        __syncthreads();
    }
#pragma unroll
    for (int jn = 0; jn < 2; ++jn) {
        int j = n0 + wc * 32 + jn * 16 + l15;   // [0,192)
        int g = j >> 6, d = j & 63;
        __hip_bfloat16* outp = qout + (long)g * 2097152 + (long)z * 64 + d;
#pragma unroll
        for (int im = 0; im < 4; ++im)
#pragma unroll
            for (int reg = 0; reg < 4; ++reg) {
                long m = m0 + wr * 64 + im * 16 + l4 * 4 + reg;
                outp[m * 512] = __float2bfloat16(acc[im][jn][reg]);
            }
    }
}

// ---------------------------------------------------------------------------
// MFMA big GEMM + fused GRU epilogue — 32x32x16 MFMA, fragment-major LDS.
// Block: 256 thr / 4 waves (2m x 2n), tile 128m x (64ol x 3g = 192n).
// Wave: 64m x 96n = 2 A-frags x 3 B-frags per k16 -> 6 MFMAs / 5 KB LDS reads.
// LDS: A 16 frags (4 rowblk x 4 kblk) + B 24 frags, each contiguous 1 KB ->
// conflict-free ds_read_b128 at base+frag*1024+lane*16. XCD-pinned kblk=bid&7.
// Gates r,z use a MERGED accumulator (scale by av between phases); gate n
// keeps x/h parts separate (r multiplies only the h part).
// ---------------------------------------------------------------------------
__global__ __launch_bounds__(256) void gru_fused_mfma(
    const __hip_bfloat16* __restrict__ wfcb,   // (B,1024)
    const __hip_bfloat16* __restrict__ hxb,    // (B,2048)
    const float* __restrict__ a_buf,           // (B,8)
    const float* __restrict__ cb,              // (8,768)
    const __hip_bfloat16* __restrict__ Wihb,   // (8,768,1024)
    const __hip_bfloat16* __restrict__ Whhb,   // (8,768,256)
    const float* __restrict__ bhh,             // (8,768)
    __hip_bfloat16* __restrict__ hnewb)        // (B,2048)
{
    const int bid = blockIdx.x;
    const int kblk = bid & 7;
    const int r_ = bid >> 3;
    const int ol0 = (r_ & 3) * 64;
    const int m0 = (r_ >> 2) * 128;
    const int tid = threadIdx.x;
    const int lane = tid & 63, wid = tid >> 6;   // 4 waves
    const int wr = wid >> 1;   // 0..1 : 64-row group
    const int wc = wid & 1;    // 0..1 : 32-ol group
    const int l31 = lane & 31, l5 = lane >> 5;

    __shared__ __align__(16) char lds_raw[16384 + 24576];
    char* Alds = lds_raw;
    char* Blds = lds_raw + 16384;

    f32x16 accm[2][2] = {};   // merged r,z gates
    f32x16 acc2x[2] = {};     // gate n, x-part
    f32x16 acc2h[2] = {};     // gate n, h-part

#define STAGE(Asrc, sA, Bsrc, sB, k0) do {                                     \
    for (int c = wid; c < 16; c += 4) {                                        \
        int row = (c >> 2) * 32 + l31;                                         \
        int k = (c & 3) * 16 + l5 * 8;                                         \
        const __hip_bfloat16* g = (Asrc) + (long)(m0 + row) * (sA) + (k0) + k; \
        GLDS16(g, Alds + c * 1024);                                            \
    }                                                                          \
    for (int c = wid; c < 24; c += 4) {                                        \
        int row = (c >> 2) * 32 + l31;                                         \
        int k = (c & 3) * 16 + l5 * 8;                                         \
        int gg = row >> 6, oll = row & 63;                                     \
        const __hip_bfloat16* g = (Bsrc) + (long)(gg * 256 + ol0 + oll) * (sB) + (k0) + k; \
        GLDS16(g, Blds + c * 1024);                                            \
    }                                                                          \
} while (0)

#define COMPUTE(A2) do {                                                       \
    _Pragma("unroll") for (int kk = 0; kk < 4; ++kk) {                         \
        bf16x8 af[2], bfr[3];                                                  \
        _Pragma("unroll") for (int im = 0; im < 2; ++im)                       \
            af[im] = *(const bf16x8*)(Alds + ((wr * 2 + im) * 4 + kk) * 1024 + lane * 16); \
        _Pragma("unroll") for (int g = 0; g < 3; ++g)                          \
            bfr[g] = *(const bf16x8*)(Blds + ((g * 2 + wc) * 4 + kk) * 1024 + lane * 16);  \
        _Pragma("unroll") for (int im = 0; im < 2; ++im) {                     \
            accm[im][0] = __builtin_amdgcn_mfma_f32_32x32x16_bf16(             \
                af[im], bfr[0], accm[im][0], 0, 0, 0);                         \
            accm[im][1] = __builtin_amdgcn_mfma_f32_32x32x16_bf16(             \
                af[im], bfr[1], accm[im][1], 0, 0, 0);                         \
            A2[im] = __builtin_amdgcn_mfma_f32_32x32x16_bf16(                  \
                af[im], bfr[2], A2[im], 0, 0, 0);                              \
        }                                                                      \
    }                                                                          \
} while (0)

    // Phase 1: gx = wfc @ Wih[kblk]^T, K=1024
    const __hip_bfloat16* Wk = Wihb + (long)kblk * 768 * 1024;
    for (int k0 = 0; k0 < 1024; k0 += 64) {
        STAGE(wfcb, 1024, Wk, 1024, k0);
        __syncthreads();
        COMPUTE(acc2x);
        __syncthreads();
    }
    // Scale x-parts by per-row av (gates r,z merge; gate-n x kept separate)
#pragma unroll
    for (int im = 0; im < 2; ++im) {
#pragma unroll
        for (int reg = 0; reg < 16; ++reg) {
            long m = m0 + wr * 64 + im * 32 + (reg & 3) + 8 * (reg >> 2) + 4 * l5;
            float av = a_buf[m * 8 + kblk];
            accm[im][0][reg] *= av;
            accm[im][1][reg] *= av;
            acc2x[im][reg] *= av;
        }
    }
    // Phase 2: gh = hx[:,kblk*256:+256] @ Whh[kblk]^T, K=256 (accumulates)
    const __hip_bfloat16* Wh = Whhb + (long)kblk * 768 * 256;
    const __hip_bfloat16* hxk = hxb + kblk * 256;
    for (int k0 = 0; k0 < 256; k0 += 64) {
        STAGE(hxk, 2048, Wh, 256, k0);
        __syncthreads();
        COMPUTE(acc2h);
        __syncthreads();
    }
#undef STAGE
#undef COMPUTE

    // Epilogue: GRU nonlinearity.  C/D layout (32x32): col=lane&31,
    // row=(reg&3)+8*(reg>>2)+4*(lane>>5)   [guide §3, m74/m101 verified]
    const int ol = ol0 + wc * 32 + l31;
    const float* cbk = cb + kblk * 768;
    const float* bhk = bhh + kblk * 768;
    const float cb0 = cbk[ol], cb1 = cbk[256 + ol], cb2 = cbk[512 + ol];
    const float bh0 = bhk[ol], bh1 = bhk[256 + ol], bh2 = bhk[512 + ol];
#pragma unroll
    for (int im = 0; im < 2; ++im) {
#pragma unroll
        for (int reg = 0; reg < 16; ++reg) {
            long m = m0 + wr * 64 + im * 32 + (reg & 3) + 8 * (reg >> 2) + 4 * l5;
            float rr = sigmoidf_(accm[im][0][reg] + cb0 + bh0);
            float zz = sigmoidf_(accm[im][1][reg] + cb1 + bh1);
            float nn = tanhf(acc2x[im][reg] + cb2 + rr * (acc2h[im][reg] + bh2));
            long idx = m * 2048 + kblk * 256 + ol;
            float hxv = __bfloat162float(hxb[idx]);
            hnewb[idx] = __float2bfloat16((1.f - zz) * nn + zz * hxv);
        }
    }
}

// ---------------------------------------------------------------------------
// Memory attention (bf16 in/out)
// ---------------------------------------------------------------------------
__global__ __launch_bounds__(256) void mattn_kernel(
    const __hip_bfloat16* __restrict__ qm, const __hip_bfloat16* __restrict__ km,
    const __hip_bfloat16* __restrict__ vm, __hip_bfloat16* __restrict__ omb)
{
    const int t = threadIdx.x;
    const int local = t & 31;
    const long b = (long)blockIdx.x * 8 + (t >> 5);
    const int h = local >> 3, qn = local & 7;
    const long base = b * 512 + h * 16;

    float qv[16];
#pragma unroll
    for (int i = 0; i < 2; ++i) {
        bf16x8 v = *(const bf16x8*)(qm + base + qn * 64 + i * 8);
#pragma unroll
        for (int j = 0; j < 8; ++j) qv[i * 8 + j] = (float)v[j];
    }
    float sc[8];
#pragma unroll
    for (int kn = 0; kn < 8; ++kn) {
        float s = 0.f;
#pragma unroll
        for (int i = 0; i < 2; ++i) {
            bf16x8 v = *(const bf16x8*)(km + base + kn * 64 + i * 8);
#pragma unroll
            for (int j = 0; j < 8; ++j) s += qv[i * 8 + j] * (float)v[j];
        }
        sc[kn] = s * 0.25f;
    }
    float mx = sc[0];
#pragma unroll
    for (int kn = 1; kn < 8; ++kn) mx = fmaxf(mx, sc[kn]);
    float ssum = 0.f;
#pragma unroll
    for (int kn = 0; kn < 8; ++kn) { sc[kn] = expf(sc[kn] - mx); ssum += sc[kn]; }
    float inv = 1.f / ssum;

    float acc[16] = {};
#pragma unroll
    for (int kn = 0; kn < 8; ++kn) {
        float w = sc[kn] * inv;
#pragma unroll
        for (int i = 0; i < 2; ++i) {
            bf16x8 v = *(const bf16x8*)(vm + base + kn * 64 + i * 8);
#pragma unroll
            for (int j = 0; j < 8; ++j) acc[i * 8 + j] += w * (float)v[j];
        }
    }
#pragma unroll
    for (int i = 0; i < 2; ++i) {
        bf16x8 o;
#pragma unroll
        for (int j = 0; j < 8; ++j) o[j] = (__bf16)acc[i * 8 + j];
        *(bf16x8*)(omb + base + qn * 64 + i * 8) = o;
    }
}

// ---------------------------------------------------------------------------
// att GEMM: (32768 x 64) om @ fcgT(512x64)^T with fused sig*tanh epilogue.
// ---------------------------------------------------------------------------
__global__ __launch_bounds__(256) void att_gemm(
    const __hip_bfloat16* __restrict__ omb,    // (32768,64)
    const __hip_bfloat16* __restrict__ fcgT,   // (512,64)
    const float* __restrict__ fc_b, const float* __restrict__ gate_b,
    __hip_bfloat16* __restrict__ attb)         // (32768,256) == (B,2048)
{
    const int m0 = blockIdx.y * 128;
    const int n0 = blockIdx.x * 64;
    const int tid = threadIdx.x;
    const int lane = tid & 63, wid = tid >> 6;
    const int wr = wid >> 1, wc = wid & 1;
    const int l15 = lane & 15, l4 = lane >> 4;

    __shared__ __align__(16) char lds_raw[16384 + 8192];
    char* Alds = lds_raw;
    char* Blds = lds_raw + 16384;

    f32x4 acc[4][2] = {};
#pragma unroll
    for (int ii = 0; ii < 4; ++ii) {
        int issue = ii * 4 + wid;
        int chunk = issue * 64 + lane;
        int r = chunk >> 3, cs = chunk & 7;
        int cl = cs ^ (r & 7);
        const __hip_bfloat16* g = omb + (long)(m0 + r) * 64 + cl * 8;
        GLDS16(g, Alds + issue * 1024);
    }
#pragma unroll
    for (int jj = 0; jj < 2; ++jj) {
        int issue = jj * 4 + wid;
        int chunk = issue * 64 + lane;
        int r = chunk >> 3, cs = chunk & 7;
        int cl = cs ^ (r & 7);
        const __hip_bfloat16* g = fcgT + (long)(n0 + r) * 64 + cl * 8;
        GLDS16(g, Blds + issue * 1024);
    }
    __syncthreads();
#pragma unroll
    for (int kk = 0; kk < 2; ++kk) {
        bf16x8 af[4], bfr[2];
#pragma unroll
        for (int im = 0; im < 4; ++im) {
            int r = wr * 64 + im * 16 + l15;
            int cl = (kk * 4 + l4) ^ (l15 & 7);
            af[im] = *(const bf16x8*)(Alds + r * 128 + cl * 16);
        }
#pragma unroll
        for (int jn = 0; jn < 2; ++jn) {
            int r = wc * 32 + jn * 16 + l15;
            int cl = (kk * 4 + l4) ^ (l15 & 7);
            bfr[jn] = *(const bf16x8*)(Blds + r * 128 + cl * 16);
        }
#pragma unroll
        for (int im = 0; im < 4; ++im)
#pragma unroll
            for (int jn = 0; jn < 2; ++jn)
                acc[im][jn] = __builtin_amdgcn_mfma_f32_16x16x32_bf16(
                    af[im], bfr[jn], acc[im][jn], 0, 0, 0);
    }
    const int o = ((n0 + wc * 32) >> 1) + l15;
    const float fb = fc_b[o], gb = gate_b[o];
#pragma unroll
    for (int im = 0; im < 4; ++im)
#pragma unroll
        for (int reg = 0; reg < 4; ++reg) {
            long m = m0 + wr * 64 + im * 16 + l4 * 4 + reg;
            float att = sigmoidf_(acc[im][1][reg] + gb) * tanhf(acc[im][0][reg] + fb);
            attb[m * 256 + o] = __float2bfloat16(att);
        }
}

// ---------------------------------------------------------------------------
// Final elementwise: h2 = hnewb + attb; masked select; mask_w write.
// ---------------------------------------------------------------------------
__global__ __launch_bounds__(256) void final_elem(
    const __hip_bfloat16* __restrict__ hnewb, const __hip_bfloat16* __restrict__ attb,
    const float* __restrict__ maskb,
    const float* __restrict__ hx, const float* __restrict__ cx,
    float* __restrict__ hx_out, float* __restrict__ cx_out, float* __restrict__ mask_w)
{
    long i4 = (long)blockIdx.x * 256 + threadIdx.x;   // 2,097,152 quads
    long e = i4 * 4;
    int n = (int)((e >> 8) & 7);
    long b = e >> 11;
    float mv = maskb[b * 8 + n];
    ushort4 hn = ((const ushort4*)hnewb)[i4];
    ushort4 at = ((const ushort4*)attb)[i4];
    float4 hxv = ((const float4*)hx)[i4];
    float4 cxv = ((const float4*)cx)[i4];
    float4 h2;
    h2.x = b2f_(hn.x) + b2f_(at.x);
    h2.y = b2f_(hn.y) + b2f_(at.y);
    h2.z = b2f_(hn.z) + b2f_(at.z);
    h2.w = b2f_(hn.w) + b2f_(at.w);
    bool k = (mv != 0.f);
    float4 ho = k ? h2 : hxv;
    float4 co = k ? h2 : cxv;
    ((float4*)hx_out)[i4] = ho;
    ((float4*)cx_out)[i4] = co;
    ((float4*)mask_w)[i4] = make_float4(mv, mv, mv, mv);
}

// ---------------------------------------------------------------------------
extern "C" void kernel_launch(void* const* d_in, const int* in_sizes, int n_in,
                              void* d_out, int out_size, void* d_ws, size_t ws_size,
                              hipStream_t stream)
{
    const float* inp     = (const float*)d_in[0];
    const float* hx      = (const float*)d_in[1];
    const float* cx      = (const float*)d_in[2];
    const float* Wq_i    = (const float*)d_in[4];
    const float* Wk_i    = (const float*)d_in[5];
    const float* Wv_i    = (const float*)d_in[6];
    const float* fc_i_w  = (const float*)d_in[7];
    const float* fc_i_b  = (const float*)d_in[8];
    const float* Wq_m    = (const float*)d_in[9];
    const float* Wk_m    = (const float*)d_in[10];
    const float* Wv_m    = (const float*)d_in[11];
    const float* fc_m_w  = (const float*)d_in[12];
    const float* fc_m_b  = (const float*)d_in[13];
    const float* gate_m_w= (const float*)d_in[14];
    const float* gate_m_b= (const float*)d_in[15];
    const float* Wih     = (const float*)d_in[16];
    const float* Whh     = (const float*)d_in[17];
    const float* bih     = (const float*)d_in[18];
    const float* bhh     = (const float*)d_in[19];

    float* out = (float*)d_out;
    const long BH = (long)B_SZ * NHID_;   // 8388608
    float* hx_out = out;
    float* cx_out = out + BH;
    float* mask_w = out + 2 * BH;
    __hip_bfloat16* hxb = (__hip_bfloat16*)out;   // bf16 hx in hx_out region (dead after gru)
    __hip_bfloat16* qkvb = (__hip_bfloat16*)out;  // q|k|v bf16, written post-gru
    float* pbuf = cx_out;                         // (B,2048) f32 p, dead before final_elem

    // Workspace layout (float offsets; all sizes exact):
    float* w = (float*)d_ws;
    float* a_buf = w;                                        // [0, 32768)
    float* maskb = w + 32768;                                // [32768, 65536)
    float* cbuf  = w + 65536;                                // [65536, 71680)
    __hip_bfloat16* fcgT = (__hip_bfloat16*)(w + 73728);     // 32768 bf16   -> [73728, 90112)
    __hip_bfloat16* WmT  = (__hip_bfloat16*)(w + 90112);     // 393216 bf16  -> [90112, 286720)
    __hip_bfloat16* Wihb = (__hip_bfloat16*)(w + 286720);    // 6291456 bf16 -> [286720, 3432448)
    __hip_bfloat16* Whhb = (__hip_bfloat16*)(w + 3432448);   // 1572864 bf16 -> [3432448, 4218880)
    __hip_bfloat16* wfcb = (__hip_bfloat16*)(w + 4218880);   // 4194304 bf16 -> [4218880, 6316032)
    __hip_bfloat16* hnewb= (__hip_bfloat16*)(w + 6316032);   // 8388608 bf16 -> [6316032, 10510336)
    // pre-gru overlays inside hnewb's region (dead before gru writes hnewb):
    float* krow = w + 8413184;                               // [8413184, 8675328)
    __hip_bfloat16* inpb = (__hip_bfloat16*)(w + 8675328);   // 2097152 bf16 -> [8675328, 9723904)
    __hip_bfloat16* WvB  = (__hip_bfloat16*)(w + 9723904);   // 524288 bf16  -> [9723904, 9986048)
    __hip_bfloat16* fcT  = (__hip_bfloat16*)(w + 9986048);   // 1048576 bf16 -> [9986048, 10510336)
    __hip_bfloat16* WvFT = (__hip_bfloat16*)(w + 10510336);  // 524288 bf16  -> [10510336, 10772480)
    // post-gru overlays (Wihb/Whhb/wfcb dead):
    __hip_bfloat16* omb  = (__hip_bfloat16*)(w + 286720);    // 2097152 bf16 -> [286720, 1335296)
    __hip_bfloat16* attb = (__hip_bfloat16*)(w + 1335296);   // 8388608 bf16 -> [1335296, 5529600)

    // ---- Phase A: conversions / prep ----
    wih_prep<<<dim3(6144), dim3(256), 0, stream>>>(Wih, fc_i_b, bih, Wihb, cbuf);
    f2b_kernel<<<dim3(2048), dim3(256), 0, stream>>>(hx, hxb, 2097152);
    f2b_kernel<<<dim3(1024), dim3(256), 0, stream>>>(inp, inpb, 524288);
    f2b_kernel<<<dim3(1024), dim3(256), 0, stream>>>(Whh, Whhb, 393216);
    f2b_kernel<<<dim3(512), dim3(256), 0, stream>>>(Wv_i + 512 * 1024, WvB, 131072);
    tconv_kernel<<<dim3(32, 32, 1), dim3(256), 0, stream>>>(fc_i_w, 1024, 0, fcT, 1024, 0);
    tconv_kernel<<<dim3(2, 8, 8), dim3(256), 0, stream>>>(Wq_m, 64, 16384, WmT, 256, 49152);
    tconv_kernel<<<dim3(2, 8, 8), dim3(256), 0, stream>>>(Wk_m, 64, 16384, WmT + 64 * 256, 256, 49152);
    tconv_kernel<<<dim3(2, 8, 8), dim3(256), 0, stream>>>(Wv_m, 64, 16384, WmT + 128 * 256, 256, 49152);
    fcg_prep<<<dim3(128), dim3(256), 0, stream>>>(fc_m_w, gate_m_w, fcgT);
    // ---- Phase B: mask path (fp32, reordered contraction) ----
    gemm_nn<<<dim3(1, 64, 1), dim3(256), 0, stream>>>(
        inp, Wk_i + 512 * 64, krow, 4096, 64, 512, 512, 64, 64, 0, 0, 0);
    gemm_nt_f32<<<dim3(4, 64, 8), dim3(256), 0, stream>>>(
        krow, 64, Wq_i, 64, pbuf, 2048, 64, 16384, 256);
    s1_mask_fused<<<dim3(1024), dim3(256), 0, stream>>>(hx, pbuf, a_buf, maskb);
    // WvFT(1024x512) = fcT(1024x1024) @ WvB(512x1024)^T
    gemm_mfma_obf16<<<dim3(8, 8, 1), dim3(256), 0, stream>>>(
        fcT, 1024, WvB, 1024, WvFT, 512, 1024);
    // wfcb(4096x1024) = inpb(4096x512) @ WvFT^T
    gemm_mfma_obf16<<<dim3(16, 32, 1), dim3(256), 0, stream>>>(
        inpb, 512, WvFT, 512, wfcb, 1024, 512);
    // ---- Phase C: fused MFMA GEMM + GRU -> hnewb (32x32 frag-major) ----
    gru_fused_mfma<<<dim3(1024), dim3(256), 0, stream>>>(
        wfcb, hxb, a_buf, cbuf, Wihb, Whhb, bhh, hnewb);
    // ---- Phase D: q/k/v_m projections (bf16, into hx_out region) ----
    gemm_mfma_qkv<<<dim3(3, 32, 8), dim3(256), 0, stream>>>(hnewb, WmT, qkvb);
    // ---- Phase E: memory attention + att GEMM + final ----
    mattn_kernel<<<dim3(512), dim3(256), 0, stream>>>(
        qkvb, qkvb + 2097152, qkvb + 4194304, omb);
    att_gemm<<<dim3(8, 256, 1), dim3(256), 0, stream>>>(omb, fcgT, fc_m_b, gate_m_b, attb);
    final_elem<<<dim3(8192), dim3(256), 0, stream>>>(
        hnewb, attb, maskb, hx, cx, hx_out, cx_out, mask_w);
}

// Round 10
// 285.816 us; speedup vs baseline: 1.3374x; 1.3374x over previous
//
#include <hip/hip_runtime.h>
#include <hip/hip_bf16.h>

#define B_SZ 4096
#define NHID_ 2048

typedef __bf16 bf16x8 __attribute__((ext_vector_type(8)));
typedef float f32x4 __attribute__((ext_vector_type(4)));

__device__ __forceinline__ float sigmoidf_(float x) { return 1.f / (1.f + expf(-x)); }
__device__ __forceinline__ float b2f_(unsigned short u) {
    unsigned v = (unsigned)u << 16;
    return __builtin_bit_cast(float, v);
}

#define GLDS16(gp, lp) __builtin_amdgcn_global_load_lds( \
    (const __attribute__((address_space(1))) void*)(gp), \
    (__attribute__((address_space(3))) void*)(lp), 16, 0, 0)

// ---------------------------------------------------------------------------
// fp32 -> bf16 conversion, 4 elems/thread, grid-stride
// ---------------------------------------------------------------------------
__global__ __launch_bounds__(256) void f2b_kernel(
    const float* __restrict__ src, __hip_bfloat16* __restrict__ dst, long n4)
{
    long i = (long)blockIdx.x * 256 + threadIdx.x;
    const long stride = (long)gridDim.x * 256;
    for (; i < n4; i += stride) {
        float4 v = ((const float4*)src)[i];
        __hip_bfloat16 b0 = __float2bfloat16(v.x);
        __hip_bfloat16 b1 = __float2bfloat16(v.y);
        __hip_bfloat16 b2 = __float2bfloat16(v.z);
        __hip_bfloat16 b3 = __float2bfloat16(v.w);
        ushort4 u;
        u.x = *(unsigned short*)&b0; u.y = *(unsigned short*)&b1;
        u.z = *(unsigned short*)&b2; u.w = *(unsigned short*)&b3;
        ((ushort4*)dst)[i] = u;
    }
}

// ---------------------------------------------------------------------------
// Wih convert + cb: Wihb = bf16(Wih); cb[j] = dot(fc_i_b, Wih[j,:]) + bih[j]
// ---------------------------------------------------------------------------
__global__ __launch_bounds__(256) void wih_prep(
    const float* __restrict__ Wih, const float* __restrict__ fc_i_b,
    const float* __restrict__ bih, __hip_bfloat16* __restrict__ Wihb,
    float* __restrict__ cb)
{
    long j = blockIdx.x;
    const float* row = Wih + j * 1024;
    __hip_bfloat16* drow = Wihb + j * 1024;
    int i = threadIdx.x * 4;
    float4 v = *(const float4*)(row + i);
    __hip_bfloat16 b0 = __float2bfloat16(v.x);
    __hip_bfloat16 b1 = __float2bfloat16(v.y);
    __hip_bfloat16 b2 = __float2bfloat16(v.z);
    __hip_bfloat16 b3 = __float2bfloat16(v.w);
    ushort4 u;
    u.x = *(unsigned short*)&b0; u.y = *(unsigned short*)&b1;
    u.z = *(unsigned short*)&b2; u.w = *(unsigned short*)&b3;
    *(ushort4*)(drow + i) = u;
    float s = fc_i_b[i] * v.x + fc_i_b[i + 1] * v.y +
              fc_i_b[i + 2] * v.z + fc_i_b[i + 3] * v.w;
#pragma unroll
    for (int off = 32; off > 0; off >>= 1) s += __shfl_xor(s, off, 64);
    __shared__ float red[4];
    if ((threadIdx.x & 63) == 0) red[threadIdx.x >> 6] = s;
    __syncthreads();
    if (threadIdx.x == 0) cb[j] = red[0] + red[1] + red[2] + red[3] + bih[j];
}

// ---------------------------------------------------------------------------
// Transpose + convert: dst[c*ldd + r] (bf16) = src[r*C + c] (f32), batched z.
// ---------------------------------------------------------------------------
__global__ __launch_bounds__(256) void tconv_kernel(
    const float* __restrict__ src, int C, long sS,
    __hip_bfloat16* __restrict__ dst, int ldd, long sD)
{
    src += (long)blockIdx.z * sS;
    dst += (long)blockIdx.z * sD;
    const int r0 = blockIdx.y * 32, c0 = blockIdx.x * 32;
    const int tx = threadIdx.x & 31, ty = threadIdx.x >> 5;
    __shared__ float tile[32][33];
#pragma unroll
    for (int i = 0; i < 4; ++i)
        tile[ty + i * 8][tx] = src[(long)(r0 + ty + i * 8) * C + c0 + tx];
    __syncthreads();
#pragma unroll
    for (int i = 0; i < 4; ++i)
        dst[(long)(c0 + ty + i * 8) * ldd + r0 + tx] = __float2bfloat16(tile[tx][ty + i * 8]);
}

// ---------------------------------------------------------------------------
// Build fcgT (512 x 64)
// ---------------------------------------------------------------------------
__global__ __launch_bounds__(256) void fcg_prep(
    const float* __restrict__ fc_w, const float* __restrict__ gate_w,
    __hip_bfloat16* __restrict__ fcgT)
{
    int tid = blockIdx.x * 256 + threadIdx.x;  // 32768
    int np = tid >> 6, k = tid & 63;
    int o = (np >> 5) * 16 + (np & 15);
    const float* src = ((np >> 4) & 1) ? gate_w : fc_w;
    fcgT[tid] = __float2bfloat16(src[k * 256 + o]);
}

// ---------------------------------------------------------------------------
// Generic fp32 tiled GEMM (krow only)
// ---------------------------------------------------------------------------
#define GM_BM 64
#define GM_BN 64
#define GM_BK 16

__global__ __launch_bounds__(256) void gemm_nn(
    const float* __restrict__ A, const float* __restrict__ Bm, float* __restrict__ C,
    int M, int N, int K, int lda, int ldb, int ldc,
    long sA, long sB, long sC)
{
    const int z = blockIdx.z;
    A += (long)z * sA; Bm += (long)z * sB; C += (long)z * sC;
    const int m0 = blockIdx.y * GM_BM;
    const int n0 = blockIdx.x * GM_BN;
    const int tid = threadIdx.x;
    const int tx = tid & 15;
    const int ty = tid >> 4;

    __shared__ float As[GM_BK][GM_BM + 4];
    __shared__ float Bs[GM_BK][GM_BN + 4];

    float acc[4][4] = {};

    for (int k0 = 0; k0 < K; k0 += GM_BK) {
#pragma unroll
        for (int i = 0; i < 4; ++i) {
            int idx = tid + i * 256;
            int r = idx >> 4, c = idx & 15;
            As[c][r] = A[(long)(m0 + r) * lda + k0 + c];
        }
#pragma unroll
        for (int i = 0; i < 4; ++i) {
            int idx = tid + i * 256;
            int r = idx >> 6, c = idx & 63;
            Bs[r][c] = Bm[(long)(k0 + r) * ldb + n0 + c];
        }
        __syncthreads();
#pragma unroll
        for (int kk = 0; kk < GM_BK; ++kk) {
            float4 a4 = *(const float4*)&As[kk][ty * 4];
            float4 b4 = *(const float4*)&Bs[kk][tx * 4];
            float av[4] = {a4.x, a4.y, a4.z, a4.w};
            float bv[4] = {b4.x, b4.y, b4.z, b4.w};
#pragma unroll
            for (int i = 0; i < 4; ++i)
#pragma unroll
                for (int j = 0; j < 4; ++j)
                    acc[i][j] += av[i] * bv[j];
        }
        __syncthreads();
    }
#pragma unroll
    for (int i = 0; i < 4; ++i) {
        long m = m0 + ty * 4 + i;
#pragma unroll
        for (int j = 0; j < 4; ++j) {
            int n = n0 + tx * 4 + j;
            C[m * ldc + n] = acc[i][j];
        }
    }
}

// ---------------------------------------------------------------------------
// fp32 GEMM with N-major B: C(MxN) = A(MxK) @ BT(NxK)^T, batched z over BT/C.
// ---------------------------------------------------------------------------
__global__ __launch_bounds__(256) void gemm_nt_f32(
    const float* __restrict__ A, int lda,
    const float* __restrict__ BT, int ldb,
    float* __restrict__ C, int ldc, int K, long sB, long sC)
{
    BT += (long)blockIdx.z * sB;
    C  += (long)blockIdx.z * sC;
    const int m0 = blockIdx.y * 64;
    const int n0 = blockIdx.x * 64;
    const int tid = threadIdx.x;
    const int tx = tid & 15;
    const int ty = tid >> 4;

    __shared__ float As[16][68];
    __shared__ float Bs[64][17];

    float acc[4][4] = {};

    for (int k0 = 0; k0 < K; k0 += 16) {
#pragma unroll
        for (int i = 0; i < 4; ++i) {
            int idx = tid + i * 256;
            int r = idx >> 4, c = idx & 15;
            As[c][r] = A[(long)(m0 + r) * lda + k0 + c];
        }
#pragma unroll
        for (int i = 0; i < 4; ++i) {
            int idx = tid + i * 256;
            int r = idx >> 4, c = idx & 15;
            Bs[r][c] = BT[(long)(n0 + r) * ldb + k0 + c];
        }
        __syncthreads();
#pragma unroll
        for (int kk = 0; kk < 16; ++kk) {
            float4 a4 = *(const float4*)&As[kk][ty * 4];
            float av[4] = {a4.x, a4.y, a4.z, a4.w};
            float bv[4];
#pragma unroll
            for (int j = 0; j < 4; ++j) bv[j] = Bs[tx * 4 + j][kk];
#pragma unroll
            for (int i = 0; i < 4; ++i)
#pragma unroll
                for (int j = 0; j < 4; ++j)
                    acc[i][j] += av[i] * bv[j];
        }
        __syncthreads();
    }
#pragma unroll
    for (int i = 0; i < 4; ++i) {
        long m = m0 + ty * 4 + i;
#pragma unroll
        for (int j = 0; j < 4; ++j) {
            int n = n0 + tx * 4 + j;
            C[m * ldc + n] = acc[i][j];
        }
    }
}

// ---------------------------------------------------------------------------
// Fused s1 / sigmoid / top-k mask + hx->bf16 emit (reads all of hx anyway).
// s1[b,n] = (hx3[b,n,:] . p[b,n,:]) / 8.
// ---------------------------------------------------------------------------
__global__ __launch_bounds__(256) void s1_mask_fused(
    const float* __restrict__ hx,   // (B,2048)
    const float* __restrict__ p,    // (B,2048)  p[b, n*256+i]
    float* __restrict__ a_buf, float* __restrict__ mask_buf,
    __hip_bfloat16* __restrict__ hxb)   // (B,2048) bf16 out
{
    const int wave = threadIdx.x >> 6;
    const int lane = threadIdx.x & 63;
    const long b = (long)blockIdx.x * 4 + wave;
    const long base = b * 2048 + lane * 4;
    float s1v[8];
#pragma unroll
    for (int n = 0; n < 8; ++n) {
        float4 hv = *(const float4*)(hx + base + n * 256);
        float4 pv = *(const float4*)(p + base + n * 256);
        // emit bf16 copy of hx
        __hip_bfloat16 c0 = __float2bfloat16(hv.x);
        __hip_bfloat16 c1 = __float2bfloat16(hv.y);
        __hip_bfloat16 c2 = __float2bfloat16(hv.z);
        __hip_bfloat16 c3 = __float2bfloat16(hv.w);
        ushort4 u;
        u.x = *(unsigned short*)&c0; u.y = *(unsigned short*)&c1;
        u.z = *(unsigned short*)&c2; u.w = *(unsigned short*)&c3;
        *(ushort4*)(hxb + base + n * 256) = u;
        float s = hv.x * pv.x + hv.y * pv.y + hv.z * pv.z + hv.w * pv.w;
#pragma unroll
        for (int off = 32; off > 0; off >>= 1) s += __shfl_xor(s, off, 64);
        s1v[n] = s * 0.125f;
    }
    unsigned maskbits = 0;
#pragma unroll
    for (int n = 0; n < 8; ++n) {
        int rank = 0;
#pragma unroll
        for (int m = 0; m < 8; ++m) {
            if (m == n) continue;
            if (s1v[m] < s1v[n] || (s1v[m] == s1v[n] && m < n)) rank++;
        }
        if (rank >= 4) maskbits |= (1u << n);
    }
    if (lane < 8) {
        float sv = s1v[0];
#pragma unroll
        for (int n = 1; n < 8; ++n)
            if (lane == n) sv = s1v[n];
        a_buf[b * 8 + lane] = sigmoidf_(sv);
        mask_buf[b * 8 + lane] = ((maskbits >> lane) & 1u) ? 1.0f : 0.0f;
    }
}

// ---------------------------------------------------------------------------
// MFMA GEMM: C(bf16, MxN) = A(bf16, MxK, lda) @ BT(bf16, NxK, ldb)^T
// ---------------------------------------------------------------------------
__global__ __launch_bounds__(256) void gemm_mfma_obf16(
    const __hip_bfloat16* __restrict__ A, int lda,
    const __hip_bfloat16* __restrict__ BT, int ldb,
    __hip_bfloat16* __restrict__ C, int ldc, int K)
{
    const int m0 = blockIdx.y * 128;
    const int n0 = blockIdx.x * 64;
    const int tid = threadIdx.x;
    const int lane = tid & 63, wid = tid >> 6;
    const int wr = wid >> 1, wc = wid & 1;
    const int l15 = lane & 15, l4 = lane >> 4;

    __shared__ __align__(16) char lds_raw[16384 + 8192];
    char* Alds = lds_raw;
    char* Blds = lds_raw + 16384;

    f32x4 acc[4][2] = {};

    for (int k0 = 0; k0 < K; k0 += 64) {
#pragma unroll
        for (int ii = 0; ii < 4; ++ii) {
            int issue = ii * 4 + wid;
            int chunk = issue * 64 + lane;
            int r = chunk >> 3, cs = chunk & 7;
            int cl = cs ^ (r & 7);
            const __hip_bfloat16* g = A + (long)(m0 + r) * lda + k0 + cl * 8;
            GLDS16(g, Alds + issue * 1024);
        }
#pragma unroll
        for (int jj = 0; jj < 2; ++jj) {
            int issue = jj * 4 + wid;
            int chunk = issue * 64 + lane;
            int r = chunk >> 3, cs = chunk & 7;
            int cl = cs ^ (r & 7);
            const __hip_bfloat16* g = BT + (long)(n0 + r) * ldb + k0 + cl * 8;
            GLDS16(g, Blds + issue * 1024);
        }
        __syncthreads();
#pragma unroll
        for (int kk = 0; kk < 2; ++kk) {
            bf16x8 af[4], bfr[2];
#pragma unroll
            for (int im = 0; im < 4; ++im) {
                int r = wr * 64 + im * 16 + l15;
                int cl = (kk * 4 + l4) ^ (l15 & 7);
                af[im] = *(const bf16x8*)(Alds + r * 128 + cl * 16);
            }
#pragma unroll
            for (int jn = 0; jn < 2; ++jn) {
                int r = wc * 32 + jn * 16 + l15;
                int cl = (kk * 4 + l4) ^ (l15 & 7);
                bfr[jn] = *(const bf16x8*)(Blds + r * 128 + cl * 16);
            }
#pragma unroll
            for (int im = 0; im < 4; ++im)
#pragma unroll
                for (int jn = 0; jn < 2; ++jn)
                    acc[im][jn] = __builtin_amdgcn_mfma_f32_16x16x32_bf16(
                        af[im], bfr[jn], acc[im][jn], 0, 0, 0);
        }
        __syncthreads();
    }
#pragma unroll
    for (int im = 0; im < 4; ++im)
#pragma unroll
        for (int reg = 0; reg < 4; ++reg) {
            long m = m0 + wr * 64 + im * 16 + l4 * 4 + reg;
#pragma unroll
            for (int jn = 0; jn < 2; ++jn) {
                int n = n0 + wc * 32 + jn * 16 + l15;
                C[m * ldc + n] = __float2bfloat16(acc[im][jn][reg]);
            }
        }
}

// ---------------------------------------------------------------------------
// Fused q/k/v_m projections (bf16 out).
// ---------------------------------------------------------------------------
__global__ __launch_bounds__(256) void gemm_mfma_qkv(
    const __hip_bfloat16* __restrict__ hnewb,  // (B,2048)
    const __hip_bfloat16* __restrict__ WmT,    // (8,192,256)
    __hip_bfloat16* __restrict__ qout)         // q|k|v, each 2097152 bf16
{
    const int z = blockIdx.z;
    const int m0 = blockIdx.y * 128;
    const int n0 = blockIdx.x * 64;
    const int tid = threadIdx.x;
    const int lane = tid & 63, wid = tid >> 6;
    const int wr = wid >> 1, wc = wid & 1;
    const int l15 = lane & 15, l4 = lane >> 4;

    const __hip_bfloat16* A = hnewb + z * 256;
    const __hip_bfloat16* BT = WmT + (long)z * 192 * 256;

    __shared__ __align__(16) char lds_raw[16384 + 8192];
    char* Alds = lds_raw;
    char* Blds = lds_raw + 16384;

    f32x4 acc[4][2] = {};

    for (int k0 = 0; k0 < 256; k0 += 64) {
#pragma unroll
        for (int ii = 0; ii < 4; ++ii) {
            int issue = ii * 4 + wid;
            int chunk = issue * 64 + lane;
            int r = chunk >> 3, cs = chunk & 7;
            int cl = cs ^ (r & 7);
            const __hip_bfloat16* g = A + (long)(m0 + r) * 2048 + k0 + cl * 8;
            GLDS16(g, Alds + issue * 1024);
        }
#pragma unroll
        for (int jj = 0; jj < 2; ++jj) {
            int issue = jj * 4 + wid;
            int chunk = issue * 64 + lane;
            int r = chunk >> 3, cs = chunk & 7;
            int cl = cs ^ (r & 7);
            const __hip_bfloat16* g = BT + (long)(n0 + r) * 256 + k0 + cl * 8;
            GLDS16(g, Blds + issue * 1024);
        }
        __syncthreads();
#pragma unroll
        for (int kk = 0; kk < 2; ++kk) {
            bf16x8 af[4], bfr[2];
#pragma unroll
            for (int im = 0; im < 4; ++im) {
                int r = wr * 64 + im * 16 + l15;
                int cl = (kk * 4 + l4) ^ (l15 & 7);
                af[im] = *(const bf16x8*)(Alds + r * 128 + cl * 16);
            }
#pragma unroll
            for (int jn = 0; jn < 2; ++jn) {
                int r = wc * 32 + jn * 16 + l15;
                int cl = (kk * 4 + l4) ^ (l15 & 7);
                bfr[jn] = *(const bf16x8*)(Blds + r * 128 + cl * 16);
            }
#pragma unroll
            for (int im = 0; im < 4; ++im)
#pragma unroll
                for (int jn = 0; jn < 2; ++jn)
                    acc[im][jn] = __builtin_amdgcn_mfma_f32_16x16x32_bf16(
                        af[im], bfr[jn], acc[im][jn], 0, 0, 0);
        }
        __syncthreads();
    }
#pragma unroll
    for (int jn = 0; jn < 2; ++jn) {
        int j = n0 + wc * 32 + jn * 16 + l15;   // [0,192)
        int g = j >> 6, d = j & 63;
        __hip_bfloat16* outp = qout + (long)g * 2097152 + (long)z * 64 + d;
#pragma unroll
        for (int im = 0; im < 4; ++im)
#pragma unroll
            for (int reg = 0; reg < 4; ++reg) {
                long m = m0 + wr * 64 + im * 16 + l4 * 4 + reg;
                outp[m * 512] = __float2bfloat16(acc[im][jn][reg]);
            }
    }
}

// ---------------------------------------------------------------------------
// MFMA big GEMM + fused GRU epilogue — R7 tile (512 thr / 8 waves, wave
// 32m x 48n, block 128m x 96n) + T3 minimum-2-phase double-buffered pipeline:
// STAGE(t+1) issued BEFORE compute(t); ONE vmcnt(0)+barrier per K-step
// (loads have the whole MFMA phase to land). LDS 2 x 28KB. XCD-pinned kblk.
// ---------------------------------------------------------------------------
__global__ __launch_bounds__(512) void gru_fused_mfma(
    const __hip_bfloat16* __restrict__ wfcb,   // (B,1024)
    const __hip_bfloat16* __restrict__ hxb,    // (B,2048)
    const float* __restrict__ a_buf,           // (B,8)
    const float* __restrict__ cb,              // (8,768)
    const __hip_bfloat16* __restrict__ Wihb,   // (8,768,1024)
    const __hip_bfloat16* __restrict__ Whhb,   // (8,768,256)
    const float* __restrict__ bhh,             // (8,768)
    __hip_bfloat16* __restrict__ hnewb)        // (B,2048)
{
    const int bid = blockIdx.x;
    const int kblk = bid & 7;
    const int r_ = bid >> 3;
    const int ol0 = (r_ & 7) * 32;
    const int m0 = (r_ >> 3) * 128;
    const int tid = threadIdx.x;
    const int lane = tid & 63, wid = tid >> 6;   // wid 0..7
    const int wr = wid >> 1;                     // 0..3 : 32-row group
    const int wc = wid & 1;                      // 0..1 : 16-ol group
    const int l15 = lane & 15, l4 = lane >> 4;

    __shared__ __align__(16) char lds_raw[2 * 28672];

    f32x4 accx[2][3] = {};
    f32x4 acch[2][3] = {};

    const __hip_bfloat16* Wk = Wihb + (long)kblk * 768 * 1024;
    const __hip_bfloat16* Wh = Whhb + (long)kblk * 768 * 256;
    const __hip_bfloat16* hxk = hxb + kblk * 256;

#define STAGE_T(Asrc, sA, Bsrc, sB, k0, buf) do {                              \
    char* Al = lds_raw + (buf) * 28672;                                        \
    char* Bl = Al + 16384;                                                     \
    for (int ii = wid; ii < 16; ii += 8) {                                     \
        int chunk = ii * 64 + lane;                                            \
        int r = chunk >> 3, cs = chunk & 7;                                    \
        int cl = cs ^ (r & 7);                                                 \
        const __hip_bfloat16* g = (Asrc) + (long)(m0 + r) * (sA) + (k0) + cl * 8; \
        GLDS16(g, Al + ii * 1024);                                             \
    }                                                                          \
    for (int jj = wid; jj < 12; jj += 8) {                                     \
        int chunk = jj * 64 + lane;                                            \
        int r = chunk >> 3, cs = chunk & 7;                                    \
        int cl = cs ^ (r & 7);                                                 \
        int gg = r >> 5, oll = r & 31;                                         \
        const __hip_bfloat16* g = (Bsrc) + (long)(gg * 256 + ol0 + oll) * (sB) + (k0) + cl * 8; \
        GLDS16(g, Bl + jj * 1024);                                             \
    }                                                                          \
} while (0)

#define STAGE_IDX(t, buf) do {                                                 \
    if ((t) < 16) STAGE_T(wfcb, 1024, Wk, 1024, (t) * 64, buf);                \
    else          STAGE_T(hxk, 2048, Wh, 256, ((t) - 16) * 64, buf);           \
} while (0)

#define COMPUTE(acc, buf) do {                                                 \
    char* Al = lds_raw + (buf) * 28672;                                        \
    char* Bl = Al + 16384;                                                     \
    _Pragma("unroll") for (int kk = 0; kk < 2; ++kk) {                         \
        bf16x8 af[2], bfr[3];                                                  \
        _Pragma("unroll") for (int im = 0; im < 2; ++im) {                     \
            int r = wr * 32 + im * 16 + l15;                                   \
            int cl = (kk * 4 + l4) ^ (l15 & 7);                                \
            af[im] = *(const bf16x8*)(Al + r * 128 + cl * 16);                 \
        }                                                                      \
        _Pragma("unroll") for (int g = 0; g < 3; ++g) {                        \
            int r = g * 32 + wc * 16 + l15;                                    \
            int cl = (kk * 4 + l4) ^ (l15 & 7);                                \
            bfr[g] = *(const bf16x8*)(Bl + r * 128 + cl * 16);                 \
        }                                                                      \
        _Pragma("unroll") for (int im = 0; im < 2; ++im)                       \
            _Pragma("unroll") for (int g = 0; g < 3; ++g)                      \
                acc[im][g] = __builtin_amdgcn_mfma_f32_16x16x32_bf16(          \
                    af[im], bfr[g], acc[im][g], 0, 0, 0);                      \
    }                                                                          \
} while (0)

    // Prologue: stage tile 0 into buf 0
    STAGE_IDX(0, 0);
    asm volatile("s_waitcnt vmcnt(0)" ::: "memory");
    __syncthreads();

    int cur = 0;
    // 20 K-steps total: 16 for gx (K=1024), 4 for gh (K=256)
    for (int t = 0; t < 20; ++t) {
        if (t + 1 < 20) STAGE_IDX(t + 1, cur ^ 1);   // prefetch next tile
        __builtin_amdgcn_s_setprio(1);
        if (t < 16) COMPUTE(accx, cur);
        else        COMPUTE(acch, cur);
        __builtin_amdgcn_s_setprio(0);
        asm volatile("s_waitcnt vmcnt(0)" ::: "memory");  // prefetch landed
        __syncthreads();                                  // all reads done
        cur ^= 1;
    }
#undef STAGE_T
#undef STAGE_IDX
#undef COMPUTE

    // Epilogue (identical to R7-verified): GRU nonlinearity
    const int ol = ol0 + wc * 16 + l15;
    const float* cbk = cb + kblk * 768;
    const float cb0 = cbk[ol], cb1 = cbk[256 + ol], cb2 = cbk[512 + ol];
    const float* bhk = bhh + kblk * 768;
    const float bh0 = bhk[ol], bh1 = bhk[256 + ol], bh2 = bhk[512 + ol];
#pragma unroll
    for (int im = 0; im < 2; ++im) {
#pragma unroll
        for (int reg = 0; reg < 4; ++reg) {
            long m = m0 + wr * 32 + im * 16 + l4 * 4 + reg;
            float av = a_buf[m * 8 + kblk];
            float gx0 = av * accx[im][0][reg] + cb0;
            float gx1 = av * accx[im][1][reg] + cb1;
            float gx2 = av * accx[im][2][reg] + cb2;
            float gh0 = acch[im][0][reg] + bh0;
            float gh1 = acch[im][1][reg] + bh1;
            float gh2 = acch[im][2][reg] + bh2;
            float rr = sigmoidf_(gx0 + gh0);
            float zz = sigmoidf_(gx1 + gh1);
            float nn = tanhf(gx2 + rr * gh2);
            long idx = m * 2048 + kblk * 256 + ol;
            float hxv = __bfloat162float(hxb[idx]);
            hnewb[idx] = __float2bfloat16((1.f - zz) * nn + zz * hxv);
        }
    }
}

// ---------------------------------------------------------------------------
// Memory attention (bf16 in/out)
// ---------------------------------------------------------------------------
__global__ __launch_bounds__(256) void mattn_kernel(
    const __hip_bfloat16* __restrict__ qm, const __hip_bfloat16* __restrict__ km,
    const __hip_bfloat16* __restrict__ vm, __hip_bfloat16* __restrict__ omb)
{
    const int t = threadIdx.x;
    const int local = t & 31;
    const long b = (long)blockIdx.x * 8 + (t >> 5);
    const int h = local >> 3, qn = local & 7;
    const long base = b * 512 + h * 16;

    float qv[16];
#pragma unroll
    for (int i = 0; i < 2; ++i) {
        bf16x8 v = *(const bf16x8*)(qm + base + qn * 64 + i * 8);
#pragma unroll
        for (int j = 0; j < 8; ++j) qv[i * 8 + j] = (float)v[j];
    }
    float sc[8];
#pragma unroll
    for (int kn = 0; kn < 8; ++kn) {
        float s = 0.f;
#pragma unroll
        for (int i = 0; i < 2; ++i) {
            bf16x8 v = *(const bf16x8*)(km + base + kn * 64 + i * 8);
#pragma unroll
            for (int j = 0; j < 8; ++j) s += qv[i * 8 + j] * (float)v[j];
        }
        sc[kn] = s * 0.25f;
    }
    float mx = sc[0];
#pragma unroll
    for (int kn = 1; kn < 8; ++kn) mx = fmaxf(mx, sc[kn]);
    float ssum = 0.f;
#pragma unroll
    for (int kn = 0; kn < 8; ++kn) { sc[kn] = expf(sc[kn] - mx); ssum += sc[kn]; }
    float inv = 1.f / ssum;

    float acc[16] = {};
#pragma unroll
    for (int kn = 0; kn < 8; ++kn) {
        float w = sc[kn] * inv;
#pragma unroll
        for (int i = 0; i < 2; ++i) {
            bf16x8 v = *(const bf16x8*)(vm + base + kn * 64 + i * 8);
#pragma unroll
            for (int j = 0; j < 8; ++j) acc[i * 8 + j] += w * (float)v[j];
        }
    }
#pragma unroll
    for (int i = 0; i < 2; ++i) {
        bf16x8 o;
#pragma unroll
        for (int j = 0; j < 8; ++j) o[j] = (__bf16)acc[i * 8 + j];
        *(bf16x8*)(omb + base + qn * 64 + i * 8) = o;
    }
}

// ---------------------------------------------------------------------------
// att GEMM: (32768 x 64) om @ fcgT(512x64)^T with fused sig*tanh epilogue.
// ---------------------------------------------------------------------------
__global__ __launch_bounds__(256) void att_gemm(
    const __hip_bfloat16* __restrict__ omb,    // (32768,64)
    const __hip_bfloat16* __restrict__ fcgT,   // (512,64)
    const float* __restrict__ fc_b, const float* __restrict__ gate_b,
    __hip_bfloat16* __restrict__ attb)         // (32768,256) == (B,2048)
{
    const int m0 = blockIdx.y * 128;
    const int n0 = blockIdx.x * 64;
    const int tid = threadIdx.x;
    const int lane = tid & 63, wid = tid >> 6;
    const int wr = wid >> 1, wc = wid & 1;
    const int l15 = lane & 15, l4 = lane >> 4;

    __shared__ __align__(16) char lds_raw[16384 + 8192];
    char* Alds = lds_raw;
    char* Blds = lds_raw + 16384;

    f32x4 acc[4][2] = {};
#pragma unroll
    for (int ii = 0; ii < 4; ++ii) {
        int issue = ii * 4 + wid;
        int chunk = issue * 64 + lane;
        int r = chunk >> 3, cs = chunk & 7;
        int cl = cs ^ (r & 7);
        const __hip_bfloat16* g = omb + (long)(m0 + r) * 64 + cl * 8;
        GLDS16(g, Alds + issue * 1024);
    }
#pragma unroll
    for (int jj = 0; jj < 2; ++jj) {
        int issue = jj * 4 + wid;
        int chunk = issue * 64 + lane;
        int r = chunk >> 3, cs = chunk & 7;
        int cl = cs ^ (r & 7);
        const __hip_bfloat16* g = fcgT + (long)(n0 + r) * 64 + cl * 8;
        GLDS16(g, Blds + issue * 1024);
    }
    __syncthreads();
#pragma unroll
    for (int kk = 0; kk < 2; ++kk) {
        bf16x8 af[4], bfr[2];
#pragma unroll
        for (int im = 0; im < 4; ++im) {
            int r = wr * 64 + im * 16 + l15;
            int cl = (kk * 4 + l4) ^ (l15 & 7);
            af[im] = *(const bf16x8*)(Alds + r * 128 + cl * 16);
        }
#pragma unroll
        for (int jn = 0; jn < 2; ++jn) {
            int r = wc * 32 + jn * 16 + l15;
            int cl = (kk * 4 + l4) ^ (l15 & 7);
            bfr[jn] = *(const bf16x8*)(Blds + r * 128 + cl * 16);
        }
#pragma unroll
        for (int im = 0; im < 4; ++im)
#pragma unroll
            for (int jn = 0; jn < 2; ++jn)
                acc[im][jn] = __builtin_amdgcn_mfma_f32_16x16x32_bf16(
                    af[im], bfr[jn], acc[im][jn], 0, 0, 0);
    }
    const int o = ((n0 + wc * 32) >> 1) + l15;
    const float fb = fc_b[o], gb = gate_b[o];
#pragma unroll
    for (int im = 0; im < 4; ++im)
#pragma unroll
        for (int reg = 0; reg < 4; ++reg) {
            long m = m0 + wr * 64 + im * 16 + l4 * 4 + reg;
            float att = sigmoidf_(acc[im][1][reg] + gb) * tanhf(acc[im][0][reg] + fb);
            attb[m * 256 + o] = __float2bfloat16(att);
        }
}

// ---------------------------------------------------------------------------
// Final elementwise: h2 = hnewb + attb; masked select; mask_w write.
// ---------------------------------------------------------------------------
__global__ __launch_bounds__(256) void final_elem(
    const __hip_bfloat16* __restrict__ hnewb, const __hip_bfloat16* __restrict__ attb,
    const float* __restrict__ maskb,
    const float* __restrict__ hx, const float* __restrict__ cx,
    float* __restrict__ hx_out, float* __restrict__ cx_out, float* __restrict__ mask_w)
{
    long i4 = (long)blockIdx.x * 256 + threadIdx.x;   // 2,097,152 quads
    long e = i4 * 4;
    int n = (int)((e >> 8) & 7);
    long b = e >> 11;
    float mv = maskb[b * 8 + n];
    ushort4 hn = ((const ushort4*)hnewb)[i4];
    ushort4 at = ((const ushort4*)attb)[i4];
    float4 hxv = ((const float4*)hx)[i4];
    float4 cxv = ((const float4*)cx)[i4];
    float4 h2;
    h2.x = b2f_(hn.x) + b2f_(at.x);
    h2.y = b2f_(hn.y) + b2f_(at.y);
    h2.z = b2f_(hn.z) + b2f_(at.z);
    h2.w = b2f_(hn.w) + b2f_(at.w);
    bool k = (mv != 0.f);
    float4 ho = k ? h2 : hxv;
    float4 co = k ? h2 : cxv;
    ((float4*)hx_out)[i4] = ho;
    ((float4*)cx_out)[i4] = co;
    ((float4*)mask_w)[i4] = make_float4(mv, mv, mv, mv);
}

// ---------------------------------------------------------------------------
extern "C" void kernel_launch(void* const* d_in, const int* in_sizes, int n_in,
                              void* d_out, int out_size, void* d_ws, size_t ws_size,
                              hipStream_t stream)
{
    const float* inp     = (const float*)d_in[0];
    const float* hx      = (const float*)d_in[1];
    const float* cx      = (const float*)d_in[2];
    const float* Wq_i    = (const float*)d_in[4];
    const float* Wk_i    = (const float*)d_in[5];
    const float* Wv_i    = (const float*)d_in[6];
    const float* fc_i_w  = (const float*)d_in[7];
    const float* fc_i_b  = (const float*)d_in[8];
    const float* Wq_m    = (const float*)d_in[9];
    const float* Wk_m    = (const float*)d_in[10];
    const float* Wv_m    = (const float*)d_in[11];
    const float* fc_m_w  = (const float*)d_in[12];
    const float* fc_m_b  = (const float*)d_in[13];
    const float* gate_m_w= (const float*)d_in[14];
    const float* gate_m_b= (const float*)d_in[15];
    const float* Wih     = (const float*)d_in[16];
    const float* Whh     = (const float*)d_in[17];
    const float* bih     = (const float*)d_in[18];
    const float* bhh     = (const float*)d_in[19];

    float* out = (float*)d_out;
    const long BH = (long)B_SZ * NHID_;   // 8388608
    float* hx_out = out;
    float* cx_out = out + BH;
    float* mask_w = out + 2 * BH;
    __hip_bfloat16* hxb = (__hip_bfloat16*)out;   // bf16 hx in hx_out region (dead after gru)
    __hip_bfloat16* qkvb = (__hip_bfloat16*)out;  // q|k|v bf16, written post-gru
    float* pbuf = cx_out;                         // (B,2048) f32 p, dead before final_elem

    // Workspace layout (float offsets; all sizes exact):
    float* w = (float*)d_ws;
    float* a_buf = w;                                        // [0, 32768)
    float* maskb = w + 32768;                                // [32768, 65536)
    float* cbuf  = w + 65536;                                // [65536, 71680)
    __hip_bfloat16* fcgT = (__hip_bfloat16*)(w + 73728);     // 32768 bf16   -> [73728, 90112)
    __hip_bfloat16* WmT  = (__hip_bfloat16*)(w + 90112);     // 393216 bf16  -> [90112, 286720)
    __hip_bfloat16* Wihb = (__hip_bfloat16*)(w + 286720);    // 6291456 bf16 -> [286720, 3432448)
    __hip_bfloat16* Whhb = (__hip_bfloat16*)(w + 3432448);   // 1572864 bf16 -> [3432448, 4218880)
    __hip_bfloat16* wfcb = (__hip_bfloat16*)(w + 4218880);   // 4194304 bf16 -> [4218880, 6316032)
    __hip_bfloat16* hnewb= (__hip_bfloat16*)(w + 6316032);   // 8388608 bf16 -> [6316032, 10510336)
    // pre-gru overlays inside hnewb's region (dead before gru writes hnewb):
    float* krow = w + 8413184;                               // [8413184, 8675328)
    __hip_bfloat16* inpb = (__hip_bfloat16*)(w + 8675328);   // 2097152 bf16 -> [8675328, 9723904)
    __hip_bfloat16* WvB  = (__hip_bfloat16*)(w + 9723904);   // 524288 bf16  -> [9723904, 9986048)
    __hip_bfloat16* fcT  = (__hip_bfloat16*)(w + 9986048);   // 1048576 bf16 -> [9986048, 10510336)
    __hip_bfloat16* WvFT = (__hip_bfloat16*)(w + 10510336);  // 524288 bf16  -> [10510336, 10772480)
    // post-gru overlays (Wihb/Whhb/wfcb dead):
    __hip_bfloat16* omb  = (__hip_bfloat16*)(w + 286720);    // 2097152 bf16 -> [286720, 1335296)
    __hip_bfloat16* attb = (__hip_bfloat16*)(w + 1335296);   // 8388608 bf16 -> [1335296, 5529600)

    // ---- Phase A: conversions / prep ----
    wih_prep<<<dim3(6144), dim3(256), 0, stream>>>(Wih, fc_i_b, bih, Wihb, cbuf);
    f2b_kernel<<<dim3(1024), dim3(256), 0, stream>>>(inp, inpb, 524288);
    f2b_kernel<<<dim3(1024), dim3(256), 0, stream>>>(Whh, Whhb, 393216);
    f2b_kernel<<<dim3(512), dim3(256), 0, stream>>>(Wv_i + 512 * 1024, WvB, 131072);
    tconv_kernel<<<dim3(32, 32, 1), dim3(256), 0, stream>>>(fc_i_w, 1024, 0, fcT, 1024, 0);
    tconv_kernel<<<dim3(2, 8, 8), dim3(256), 0, stream>>>(Wq_m, 64, 16384, WmT, 256, 49152);
    tconv_kernel<<<dim3(2, 8, 8), dim3(256), 0, stream>>>(Wk_m, 64, 16384, WmT + 64 * 256, 256, 49152);
    tconv_kernel<<<dim3(2, 8, 8), dim3(256), 0, stream>>>(Wv_m, 64, 16384, WmT + 128 * 256, 256, 49152);
    fcg_prep<<<dim3(128), dim3(256), 0, stream>>>(fc_m_w, gate_m_w, fcgT);
    // ---- Phase B: mask path (fp32, reordered contraction) + hxb emit ----
    gemm_nn<<<dim3(1, 64, 1), dim3(256), 0, stream>>>(
        inp, Wk_i + 512 * 64, krow, 4096, 64, 512, 512, 64, 64, 0, 0, 0);
    gemm_nt_f32<<<dim3(4, 64, 8), dim3(256), 0, stream>>>(
        krow, 64, Wq_i, 64, pbuf, 2048, 64, 16384, 256);
    s1_mask_fused<<<dim3(1024), dim3(256), 0, stream>>>(hx, pbuf, a_buf, maskb, hxb);
    // WvFT(1024x512) = fcT(1024x1024) @ WvB(512x1024)^T
    gemm_mfma_obf16<<<dim3(8, 8, 1), dim3(256), 0, stream>>>(
        fcT, 1024, WvB, 1024, WvFT, 512, 1024);
    // wfcb(4096x1024) = inpb(4096x512) @ WvFT^T
    gemm_mfma_obf16<<<dim3(16, 32, 1), dim3(256), 0, stream>>>(
        inpb, 512, WvFT, 512, wfcb, 1024, 512);
    // ---- Phase C: fused MFMA GEMM + GRU -> hnewb (2-phase dbuf pipeline) ----
    gru_fused_mfma<<<dim3(2048), dim3(512), 0, stream>>>(
        wfcb, hxb, a_buf, cbuf, Wihb, Whhb, bhh, hnewb);
    // ---- Phase D: q/k/v_m projections (bf16, into hx_out region) ----
    gemm_mfma_qkv<<<dim3(3, 32, 8), dim3(256), 0, stream>>>(hnewb, WmT, qkvb);
    // ---- Phase E: memory attention + att GEMM + final ----
    mattn_kernel<<<dim3(512), dim3(256), 0, stream>>>(
        qkvb, qkvb + 2097152, qkvb + 4194304, omb);
    att_gemm<<<dim3(8, 256, 1), dim3(256), 0, stream>>>(omb, fcgT, fc_m_b, gate_m_b, attb);
    final_elem<<<dim3(8192), dim3(256), 0, stream>>>(
        hnewb, attb, maskb, hx, cx, hx_out, cx_out, mask_w);
}

// Round 11
// 270.056 us; speedup vs baseline: 1.4154x; 1.0584x over previous
//
#include <hip/hip_runtime.h>
#include <hip/hip_bf16.h>

#define B_SZ 4096
#define NHID_ 2048

typedef __bf16 bf16x8 __attribute__((ext_vector_type(8)));
typedef float f32x4 __attribute__((ext_vector_type(4)));

__device__ __forceinline__ float sigmoidf_(float x) { return 1.f / (1.f + expf(-x)); }
__device__ __forceinline__ float b2f_(unsigned short u) {
    unsigned v = (unsigned)u << 16;
    return __builtin_bit_cast(float, v);
}

#define GLDS16(gp, lp) __builtin_amdgcn_global_load_lds( \
    (const __attribute__((address_space(1))) void*)(gp), \
    (__attribute__((address_space(3))) void*)(lp), 16, 0, 0)

// ---------------------------------------------------------------------------
// fp32 -> bf16 conversion, 4 elems/thread, grid-stride
// ---------------------------------------------------------------------------
__global__ __launch_bounds__(256) void f2b_kernel(
    const float* __restrict__ src, __hip_bfloat16* __restrict__ dst, long n4)
{
    long i = (long)blockIdx.x * 256 + threadIdx.x;
    const long stride = (long)gridDim.x * 256;
    for (; i < n4; i += stride) {
        float4 v = ((const float4*)src)[i];
        __hip_bfloat16 b0 = __float2bfloat16(v.x);
        __hip_bfloat16 b1 = __float2bfloat16(v.y);
        __hip_bfloat16 b2 = __float2bfloat16(v.z);
        __hip_bfloat16 b3 = __float2bfloat16(v.w);
        ushort4 u;
        u.x = *(unsigned short*)&b0; u.y = *(unsigned short*)&b1;
        u.z = *(unsigned short*)&b2; u.w = *(unsigned short*)&b3;
        ((ushort4*)dst)[i] = u;
    }
}

// ---------------------------------------------------------------------------
// Wih convert + cb: Wihb = bf16(Wih); cb[j] = dot(fc_i_b, Wih[j,:]) + bih[j]
// ---------------------------------------------------------------------------
__global__ __launch_bounds__(256) void wih_prep(
    const float* __restrict__ Wih, const float* __restrict__ fc_i_b,
    const float* __restrict__ bih, __hip_bfloat16* __restrict__ Wihb,
    float* __restrict__ cb)
{
    long j = blockIdx.x;
    const float* row = Wih + j * 1024;
    __hip_bfloat16* drow = Wihb + j * 1024;
    int i = threadIdx.x * 4;
    float4 v = *(const float4*)(row + i);
    __hip_bfloat16 b0 = __float2bfloat16(v.x);
    __hip_bfloat16 b1 = __float2bfloat16(v.y);
    __hip_bfloat16 b2 = __float2bfloat16(v.z);
    __hip_bfloat16 b3 = __float2bfloat16(v.w);
    ushort4 u;
    u.x = *(unsigned short*)&b0; u.y = *(unsigned short*)&b1;
    u.z = *(unsigned short*)&b2; u.w = *(unsigned short*)&b3;
    *(ushort4*)(drow + i) = u;
    float s = fc_i_b[i] * v.x + fc_i_b[i + 1] * v.y +
              fc_i_b[i + 2] * v.z + fc_i_b[i + 3] * v.w;
#pragma unroll
    for (int off = 32; off > 0; off >>= 1) s += __shfl_xor(s, off, 64);
    __shared__ float red[4];
    if ((threadIdx.x & 63) == 0) red[threadIdx.x >> 6] = s;
    __syncthreads();
    if (threadIdx.x == 0) cb[j] = red[0] + red[1] + red[2] + red[3] + bih[j];
}

// ---------------------------------------------------------------------------
// Transpose + convert: dst[c*ldd + r] (bf16) = src[r*C + c] (f32), batched z.
// ---------------------------------------------------------------------------
__global__ __launch_bounds__(256) void tconv_kernel(
    const float* __restrict__ src, int C, long sS,
    __hip_bfloat16* __restrict__ dst, int ldd, long sD)
{
    src += (long)blockIdx.z * sS;
    dst += (long)blockIdx.z * sD;
    const int r0 = blockIdx.y * 32, c0 = blockIdx.x * 32;
    const int tx = threadIdx.x & 31, ty = threadIdx.x >> 5;
    __shared__ float tile[32][33];
#pragma unroll
    for (int i = 0; i < 4; ++i)
        tile[ty + i * 8][tx] = src[(long)(r0 + ty + i * 8) * C + c0 + tx];
    __syncthreads();
#pragma unroll
    for (int i = 0; i < 4; ++i)
        dst[(long)(c0 + ty + i * 8) * ldd + r0 + tx] = __float2bfloat16(tile[tx][ty + i * 8]);
}

// ---------------------------------------------------------------------------
// Build fcgT (512 x 64)
// ---------------------------------------------------------------------------
__global__ __launch_bounds__(256) void fcg_prep(
    const float* __restrict__ fc_w, const float* __restrict__ gate_w,
    __hip_bfloat16* __restrict__ fcgT)
{
    int tid = blockIdx.x * 256 + threadIdx.x;  // 32768
    int np = tid >> 6, k = tid & 63;
    int o = (np >> 5) * 16 + (np & 15);
    const float* src = ((np >> 4) & 1) ? gate_w : fc_w;
    fcgT[tid] = __float2bfloat16(src[k * 256 + o]);
}

// ---------------------------------------------------------------------------
// Generic fp32 tiled GEMM (krow only)
// ---------------------------------------------------------------------------
#define GM_BM 64
#define GM_BN 64
#define GM_BK 16

__global__ __launch_bounds__(256) void gemm_nn(
    const float* __restrict__ A, const float* __restrict__ Bm, float* __restrict__ C,
    int M, int N, int K, int lda, int ldb, int ldc,
    long sA, long sB, long sC)
{
    const int z = blockIdx.z;
    A += (long)z * sA; Bm += (long)z * sB; C += (long)z * sC;
    const int m0 = blockIdx.y * GM_BM;
    const int n0 = blockIdx.x * GM_BN;
    const int tid = threadIdx.x;
    const int tx = tid & 15;
    const int ty = tid >> 4;

    __shared__ float As[GM_BK][GM_BM + 4];
    __shared__ float Bs[GM_BK][GM_BN + 4];

    float acc[4][4] = {};

    for (int k0 = 0; k0 < K; k0 += GM_BK) {
#pragma unroll
        for (int i = 0; i < 4; ++i) {
            int idx = tid + i * 256;
            int r = idx >> 4, c = idx & 15;
            As[c][r] = A[(long)(m0 + r) * lda + k0 + c];
        }
#pragma unroll
        for (int i = 0; i < 4; ++i) {
            int idx = tid + i * 256;
            int r = idx >> 6, c = idx & 63;
            Bs[r][c] = Bm[(long)(k0 + r) * ldb + n0 + c];
        }
        __syncthreads();
#pragma unroll
        for (int kk = 0; kk < GM_BK; ++kk) {
            float4 a4 = *(const float4*)&As[kk][ty * 4];
            float4 b4 = *(const float4*)&Bs[kk][tx * 4];
            float av[4] = {a4.x, a4.y, a4.z, a4.w};
            float bv[4] = {b4.x, b4.y, b4.z, b4.w};
#pragma unroll
            for (int i = 0; i < 4; ++i)
#pragma unroll
                for (int j = 0; j < 4; ++j)
                    acc[i][j] += av[i] * bv[j];
        }
        __syncthreads();
    }
#pragma unroll
    for (int i = 0; i < 4; ++i) {
        long m = m0 + ty * 4 + i;
#pragma unroll
        for (int j = 0; j < 4; ++j) {
            int n = n0 + tx * 4 + j;
            C[m * ldc + n] = acc[i][j];
        }
    }
}

// ---------------------------------------------------------------------------
// fp32 GEMM with N-major B: C(MxN) = A(MxK) @ BT(NxK)^T, batched z over BT/C.
// ---------------------------------------------------------------------------
__global__ __launch_bounds__(256) void gemm_nt_f32(
    const float* __restrict__ A, int lda,
    const float* __restrict__ BT, int ldb,
    float* __restrict__ C, int ldc, int K, long sB, long sC)
{
    BT += (long)blockIdx.z * sB;
    C  += (long)blockIdx.z * sC;
    const int m0 = blockIdx.y * 64;
    const int n0 = blockIdx.x * 64;
    const int tid = threadIdx.x;
    const int tx = tid & 15;
    const int ty = tid >> 4;

    __shared__ float As[16][68];
    __shared__ float Bs[64][17];

    float acc[4][4] = {};

    for (int k0 = 0; k0 < K; k0 += 16) {
#pragma unroll
        for (int i = 0; i < 4; ++i) {
            int idx = tid + i * 256;
            int r = idx >> 4, c = idx & 15;
            As[c][r] = A[(long)(m0 + r) * lda + k0 + c];
        }
#pragma unroll
        for (int i = 0; i < 4; ++i) {
            int idx = tid + i * 256;
            int r = idx >> 4, c = idx & 15;
            Bs[r][c] = BT[(long)(n0 + r) * ldb + k0 + c];
        }
        __syncthreads();
#pragma unroll
        for (int kk = 0; kk < 16; ++kk) {
            float4 a4 = *(const float4*)&As[kk][ty * 4];
            float av[4] = {a4.x, a4.y, a4.z, a4.w};
            float bv[4];
#pragma unroll
            for (int j = 0; j < 4; ++j) bv[j] = Bs[tx * 4 + j][kk];
#pragma unroll
            for (int i = 0; i < 4; ++i)
#pragma unroll
                for (int j = 0; j < 4; ++j)
                    acc[i][j] += av[i] * bv[j];
        }
        __syncthreads();
    }
#pragma unroll
    for (int i = 0; i < 4; ++i) {
        long m = m0 + ty * 4 + i;
#pragma unroll
        for (int j = 0; j < 4; ++j) {
            int n = n0 + tx * 4 + j;
            C[m * ldc + n] = acc[i][j];
        }
    }
}

// ---------------------------------------------------------------------------
// Fused s1 / sigmoid / top-k mask + hx->bf16 emit.
// ---------------------------------------------------------------------------
__global__ __launch_bounds__(256) void s1_mask_fused(
    const float* __restrict__ hx,   // (B,2048)
    const float* __restrict__ p,    // (B,2048)  p[b, n*256+i]
    float* __restrict__ a_buf, float* __restrict__ mask_buf,
    __hip_bfloat16* __restrict__ hxb)   // (B,2048) bf16 out
{
    const int wave = threadIdx.x >> 6;
    const int lane = threadIdx.x & 63;
    const long b = (long)blockIdx.x * 4 + wave;
    const long base = b * 2048 + lane * 4;
    float s1v[8];
#pragma unroll
    for (int n = 0; n < 8; ++n) {
        float4 hv = *(const float4*)(hx + base + n * 256);
        float4 pv = *(const float4*)(p + base + n * 256);
        __hip_bfloat16 c0 = __float2bfloat16(hv.x);
        __hip_bfloat16 c1 = __float2bfloat16(hv.y);
        __hip_bfloat16 c2 = __float2bfloat16(hv.z);
        __hip_bfloat16 c3 = __float2bfloat16(hv.w);
        ushort4 u;
        u.x = *(unsigned short*)&c0; u.y = *(unsigned short*)&c1;
        u.z = *(unsigned short*)&c2; u.w = *(unsigned short*)&c3;
        *(ushort4*)(hxb + base + n * 256) = u;
        float s = hv.x * pv.x + hv.y * pv.y + hv.z * pv.z + hv.w * pv.w;
#pragma unroll
        for (int off = 32; off > 0; off >>= 1) s += __shfl_xor(s, off, 64);
        s1v[n] = s * 0.125f;
    }
    unsigned maskbits = 0;
#pragma unroll
    for (int n = 0; n < 8; ++n) {
        int rank = 0;
#pragma unroll
        for (int m = 0; m < 8; ++m) {
            if (m == n) continue;
            if (s1v[m] < s1v[n] || (s1v[m] == s1v[n] && m < n)) rank++;
        }
        if (rank >= 4) maskbits |= (1u << n);
    }
    if (lane < 8) {
        float sv = s1v[0];
#pragma unroll
        for (int n = 1; n < 8; ++n)
            if (lane == n) sv = s1v[n];
        a_buf[b * 8 + lane] = sigmoidf_(sv);
        mask_buf[b * 8 + lane] = ((maskbits >> lane) & 1u) ? 1.0f : 0.0f;
    }
}

// ---------------------------------------------------------------------------
// MFMA GEMM: C(bf16, MxN) = A(bf16, MxK, lda) @ BT(bf16, NxK, ldb)^T
// ---------------------------------------------------------------------------
__global__ __launch_bounds__(256) void gemm_mfma_obf16(
    const __hip_bfloat16* __restrict__ A, int lda,
    const __hip_bfloat16* __restrict__ BT, int ldb,
    __hip_bfloat16* __restrict__ C, int ldc, int K)
{
    const int m0 = blockIdx.y * 128;
    const int n0 = blockIdx.x * 64;
    const int tid = threadIdx.x;
    const int lane = tid & 63, wid = tid >> 6;
    const int wr = wid >> 1, wc = wid & 1;
    const int l15 = lane & 15, l4 = lane >> 4;

    __shared__ __align__(16) char lds_raw[16384 + 8192];
    char* Alds = lds_raw;
    char* Blds = lds_raw + 16384;

    f32x4 acc[4][2] = {};

    for (int k0 = 0; k0 < K; k0 += 64) {
#pragma unroll
        for (int ii = 0; ii < 4; ++ii) {
            int issue = ii * 4 + wid;
            int chunk = issue * 64 + lane;
            int r = chunk >> 3, cs = chunk & 7;
            int cl = cs ^ (r & 7);
            const __hip_bfloat16* g = A + (long)(m0 + r) * lda + k0 + cl * 8;
            GLDS16(g, Alds + issue * 1024);
        }
#pragma unroll
        for (int jj = 0; jj < 2; ++jj) {
            int issue = jj * 4 + wid;
            int chunk = issue * 64 + lane;
            int r = chunk >> 3, cs = chunk & 7;
            int cl = cs ^ (r & 7);
            const __hip_bfloat16* g = BT + (long)(n0 + r) * ldb + k0 + cl * 8;
            GLDS16(g, Blds + issue * 1024);
        }
        __syncthreads();
#pragma unroll
        for (int kk = 0; kk < 2; ++kk) {
            bf16x8 af[4], bfr[2];
#pragma unroll
            for (int im = 0; im < 4; ++im) {
                int r = wr * 64 + im * 16 + l15;
                int cl = (kk * 4 + l4) ^ (l15 & 7);
                af[im] = *(const bf16x8*)(Alds + r * 128 + cl * 16);
            }
#pragma unroll
            for (int jn = 0; jn < 2; ++jn) {
                int r = wc * 32 + jn * 16 + l15;
                int cl = (kk * 4 + l4) ^ (l15 & 7);
                bfr[jn] = *(const bf16x8*)(Blds + r * 128 + cl * 16);
            }
#pragma unroll
            for (int im = 0; im < 4; ++im)
#pragma unroll
                for (int jn = 0; jn < 2; ++jn)
                    acc[im][jn] = __builtin_amdgcn_mfma_f32_16x16x32_bf16(
                        af[im], bfr[jn], acc[im][jn], 0, 0, 0);
        }
        __syncthreads();
    }
#pragma unroll
    for (int im = 0; im < 4; ++im)
#pragma unroll
        for (int reg = 0; reg < 4; ++reg) {
            long m = m0 + wr * 64 + im * 16 + l4 * 4 + reg;
#pragma unroll
            for (int jn = 0; jn < 2; ++jn) {
                int n = n0 + wc * 32 + jn * 16 + l15;
                C[m * ldc + n] = __float2bfloat16(acc[im][jn][reg]);
            }
        }
}

// ---------------------------------------------------------------------------
// Fused q/k/v_m projections (bf16 out).
// ---------------------------------------------------------------------------
__global__ __launch_bounds__(256) void gemm_mfma_qkv(
    const __hip_bfloat16* __restrict__ hnewb,  // (B,2048)
    const __hip_bfloat16* __restrict__ WmT,    // (8,192,256)
    __hip_bfloat16* __restrict__ qout)         // q|k|v, each 2097152 bf16
{
    const int z = blockIdx.z;
    const int m0 = blockIdx.y * 128;
    const int n0 = blockIdx.x * 64;
    const int tid = threadIdx.x;
    const int lane = tid & 63, wid = tid >> 6;
    const int wr = wid >> 1, wc = wid & 1;
    const int l15 = lane & 15, l4 = lane >> 4;

    const __hip_bfloat16* A = hnewb + z * 256;
    const __hip_bfloat16* BT = WmT + (long)z * 192 * 256;

    __shared__ __align__(16) char lds_raw[16384 + 8192];
    char* Alds = lds_raw;
    char* Blds = lds_raw + 16384;

    f32x4 acc[4][2] = {};

    for (int k0 = 0; k0 < 256; k0 += 64) {
#pragma unroll
        for (int ii = 0; ii < 4; ++ii) {
            int issue = ii * 4 + wid;
            int chunk = issue * 64 + lane;
            int r = chunk >> 3, cs = chunk & 7;
            int cl = cs ^ (r & 7);
            const __hip_bfloat16* g = A + (long)(m0 + r) * 2048 + k0 + cl * 8;
            GLDS16(g, Alds + issue * 1024);
        }
#pragma unroll
        for (int jj = 0; jj < 2; ++jj) {
            int issue = jj * 4 + wid;
            int chunk = issue * 64 + lane;
            int r = chunk >> 3, cs = chunk & 7;
            int cl = cs ^ (r & 7);
            const __hip_bfloat16* g = BT + (long)(n0 + r) * 256 + k0 + cl * 8;
            GLDS16(g, Blds + issue * 1024);
        }
        __syncthreads();
#pragma unroll
        for (int kk = 0; kk < 2; ++kk) {
            bf16x8 af[4], bfr[2];
#pragma unroll
            for (int im = 0; im < 4; ++im) {
                int r = wr * 64 + im * 16 + l15;
                int cl = (kk * 4 + l4) ^ (l15 & 7);
                af[im] = *(const bf16x8*)(Alds + r * 128 + cl * 16);
            }
#pragma unroll
            for (int jn = 0; jn < 2; ++jn) {
                int r = wc * 32 + jn * 16 + l15;
                int cl = (kk * 4 + l4) ^ (l15 & 7);
                bfr[jn] = *(const bf16x8*)(Blds + r * 128 + cl * 16);
            }
#pragma unroll
            for (int im = 0; im < 4; ++im)
#pragma unroll
                for (int jn = 0; jn < 2; ++jn)
                    acc[im][jn] = __builtin_amdgcn_mfma_f32_16x16x32_bf16(
                        af[im], bfr[jn], acc[im][jn], 0, 0, 0);
        }
        __syncthreads();
    }
#pragma unroll
    for (int jn = 0; jn < 2; ++jn) {
        int j = n0 + wc * 32 + jn * 16 + l15;   // [0,192)
        int g = j >> 6, d = j & 63;
        __hip_bfloat16* outp = qout + (long)g * 2097152 + (long)z * 64 + d;
#pragma unroll
        for (int im = 0; im < 4; ++im)
#pragma unroll
            for (int reg = 0; reg < 4; ++reg) {
                long m = m0 + wr * 64 + im * 16 + l4 * 4 + reg;
                outp[m * 512] = __float2bfloat16(acc[im][jn][reg]);
            }
    }
}

// ---------------------------------------------------------------------------
// MFMA big GEMM + fused GRU epilogue — R10 sync structure (2-phase dbuf,
// one vmcnt(0)+barrier per K-step) with ALL address math hoisted:
// staging via 4 advancing pointers (+64 elems/step), LDS read offsets
// precomputed. 512 thr / 8 waves, wave 32m x 48n, XCD-pinned kblk = bid&7.
// ---------------------------------------------------------------------------
__global__ __launch_bounds__(512) void gru_fused_mfma(
    const __hip_bfloat16* __restrict__ wfcb,   // (B,1024)
    const __hip_bfloat16* __restrict__ hxb,    // (B,2048)
    const float* __restrict__ a_buf,           // (B,8)
    const float* __restrict__ cb,              // (8,768)
    const __hip_bfloat16* __restrict__ Wihb,   // (8,768,1024)
    const __hip_bfloat16* __restrict__ Whhb,   // (8,768,256)
    const float* __restrict__ bhh,             // (8,768)
    __hip_bfloat16* __restrict__ hnewb)        // (B,2048)
{
    const int bid = blockIdx.x;
    const int kblk = bid & 7;
    const int r_ = bid >> 3;
    const int ol0 = (r_ & 7) * 32;
    const int m0 = (r_ >> 3) * 128;
    const int tid = threadIdx.x;
    const int lane = tid & 63, wid = tid >> 6;   // wid 0..7
    const int wr = wid >> 1;                     // 0..3 : 32-row group
    const int wc = wid & 1;                      // 0..1 : 16-ol group
    const int l15 = lane & 15, l4 = lane >> 4;

    __shared__ __align__(16) char lds_raw[2 * 28672];

    f32x4 accx[2][3] = {};
    f32x4 acch[2][3] = {};

    const __hip_bfloat16* Wk = Wihb + (long)kblk * 768 * 1024;
    const __hip_bfloat16* Wh = Whhb + (long)kblk * 768 * 256;
    const __hip_bfloat16* hxk = hxb + kblk * 256;

    // ---- Staging geometry (thread-invariant), computed once ----
    // A chunks: ii0 = wid, ii1 = wid+8 (16 KB tile, 16 chunks of 1 KB)
    const int iiA0 = wid, iiA1 = wid + 8;
    const int cA0 = iiA0 * 64 + lane, rA0 = cA0 >> 3, clA0 = (cA0 & 7) ^ (rA0 & 7);
    const int cA1 = iiA1 * 64 + lane, rA1 = cA1 >> 3, clA1 = (cA1 & 7) ^ (rA1 & 7);
    // B chunks: jj0 = wid (all waves), jj1 = wid+8 (waves 0-3 only; 12 chunks)
    const int jjB0 = wid, jjB1 = wid + 8;
    const int cB0 = jjB0 * 64 + lane, rB0 = cB0 >> 3, clB0 = (cB0 & 7) ^ (rB0 & 7);
    const int cB1 = jjB1 * 64 + lane, rB1 = cB1 >> 3, clB1 = (cB1 & 7) ^ (rB1 & 7);
    const bool hasB1 = (wid < 4);
    const int gg0 = rB0 >> 5, oll0 = rB0 & 31;
    const int gg1 = (rB1 >> 5) & 3, oll1 = rB1 & 31;   // mask keeps ptr sane for unused lanes
    // LDS dest byte offsets (wave-uniform)
    const int dA0 = iiA0 * 1024, dA1 = iiA1 * 1024;
    const int dB0 = 16384 + jjB0 * 1024, dB1 = 16384 + jjB1 * 1024;

    // Phase-1 source pointers (advance +64 elems per K-step)
    const __hip_bfloat16* pA0 = wfcb + (long)(m0 + rA0) * 1024 + clA0 * 8;
    const __hip_bfloat16* pA1 = wfcb + (long)(m0 + rA1) * 1024 + clA1 * 8;
    const __hip_bfloat16* pB0 = Wk + (long)(gg0 * 256 + ol0 + oll0) * 1024 + clB0 * 8;
    const __hip_bfloat16* pB1 = Wk + (long)(gg1 * 256 + ol0 + oll1) * 1024 + clB1 * 8;

#define STAGE4(buf) do {                                                       \
    char* L = lds_raw + (buf) * 28672;                                         \
    GLDS16(pA0, L + dA0);                                                      \
    GLDS16(pA1, L + dA1);                                                      \
    GLDS16(pB0, L + dB0);                                                      \
    if (hasB1) GLDS16(pB1, L + dB1);                                           \
    pA0 += 64; pA1 += 64; pB0 += 64; pB1 += 64;                                \
} while (0)

    // ---- LDS read byte offsets (thread-invariant), computed once ----
    int offA[2][2], offB[2][3];
#pragma unroll
    for (int kk = 0; kk < 2; ++kk) {
        int cl = (kk * 4 + l4) ^ (l15 & 7);
#pragma unroll
        for (int im = 0; im < 2; ++im)
            offA[kk][im] = (wr * 32 + im * 16 + l15) * 128 + cl * 16;
#pragma unroll
        for (int g = 0; g < 3; ++g)
            offB[kk][g] = 16384 + (g * 32 + wc * 16 + l15) * 128 + cl * 16;
    }

#define COMPUTE(acc, buf) do {                                                 \
    char* L = lds_raw + (buf) * 28672;                                         \
    _Pragma("unroll") for (int kk = 0; kk < 2; ++kk) {                         \
        bf16x8 af[2], bfr[3];                                                  \
        _Pragma("unroll") for (int im = 0; im < 2; ++im)                       \
            af[im] = *(const bf16x8*)(L + offA[kk][im]);                       \
        _Pragma("unroll") for (int g = 0; g < 3; ++g)                          \
            bfr[g] = *(const bf16x8*)(L + offB[kk][g]);                        \
        _Pragma("unroll") for (int im = 0; im < 2; ++im)                       \
            _Pragma("unroll") for (int g = 0; g < 3; ++g)                      \
                acc[im][g] = __builtin_amdgcn_mfma_f32_16x16x32_bf16(          \
                    af[im], bfr[g], acc[im][g], 0, 0, 0);                      \
    }                                                                          \
} while (0)

    // Prologue: stage phase-1 tile 0 into buf 0
    STAGE4(0);
    asm volatile("s_waitcnt vmcnt(0)" ::: "memory");
    __syncthreads();

    int cur = 0;
    // Phase 1: 16 K-steps (gx, K=1024)
    for (int t = 0; t < 16; ++t) {
        if (t < 15) {
            STAGE4(cur ^ 1);
        } else {
            // rebuild pointers for phase 2, then stage its first tile
            pA0 = hxk + (long)(m0 + rA0) * 2048 + clA0 * 8;
            pA1 = hxk + (long)(m0 + rA1) * 2048 + clA1 * 8;
            pB0 = Wh + (long)(gg0 * 256 + ol0 + oll0) * 256 + clB0 * 8;
            pB1 = Wh + (long)(gg1 * 256 + ol0 + oll1) * 256 + clB1 * 8;
            STAGE4(cur ^ 1);
        }
        __builtin_amdgcn_s_setprio(1);
        COMPUTE(accx, cur);
        __builtin_amdgcn_s_setprio(0);
        asm volatile("s_waitcnt vmcnt(0)" ::: "memory");
        __syncthreads();
        cur ^= 1;
    }
    // Phase 2: 4 K-steps (gh, K=256)
    for (int t = 0; t < 4; ++t) {
        if (t < 3) STAGE4(cur ^ 1);
        __builtin_amdgcn_s_setprio(1);
        COMPUTE(acch, cur);
        __builtin_amdgcn_s_setprio(0);
        asm volatile("s_waitcnt vmcnt(0)" ::: "memory");
        __syncthreads();
        cur ^= 1;
    }
#undef STAGE4
#undef COMPUTE

    // Epilogue (identical to R10-verified): GRU nonlinearity
    const int ol = ol0 + wc * 16 + l15;
    const float* cbk = cb + kblk * 768;
    const float cb0 = cbk[ol], cb1 = cbk[256 + ol], cb2 = cbk[512 + ol];
    const float* bhk = bhh + kblk * 768;
    const float bh0 = bhk[ol], bh1 = bhk[256 + ol], bh2 = bhk[512 + ol];
#pragma unroll
    for (int im = 0; im < 2; ++im) {
#pragma unroll
        for (int reg = 0; reg < 4; ++reg) {
            long m = m0 + wr * 32 + im * 16 + l4 * 4 + reg;
            float av = a_buf[m * 8 + kblk];
            float gx0 = av * accx[im][0][reg] + cb0;
            float gx1 = av * accx[im][1][reg] + cb1;
            float gx2 = av * accx[im][2][reg] + cb2;
            float gh0 = acch[im][0][reg] + bh0;
            float gh1 = acch[im][1][reg] + bh1;
            float gh2 = acch[im][2][reg] + bh2;
            float rr = sigmoidf_(gx0 + gh0);
            float zz = sigmoidf_(gx1 + gh1);
            float nn = tanhf(gx2 + rr * gh2);
            long idx = m * 2048 + kblk * 256 + ol;
            float hxv = __bfloat162float(hxb[idx]);
            hnewb[idx] = __float2bfloat16((1.f - zz) * nn + zz * hxv);
        }
    }
}

// ---------------------------------------------------------------------------
// Memory attention (bf16 in/out)
// ---------------------------------------------------------------------------
__global__ __launch_bounds__(256) void mattn_kernel(
    const __hip_bfloat16* __restrict__ qm, const __hip_bfloat16* __restrict__ km,
    const __hip_bfloat16* __restrict__ vm, __hip_bfloat16* __restrict__ omb)
{
    const int t = threadIdx.x;
    const int local = t & 31;
    const long b = (long)blockIdx.x * 8 + (t >> 5);
    const int h = local >> 3, qn = local & 7;
    const long base = b * 512 + h * 16;

    float qv[16];
#pragma unroll
    for (int i = 0; i < 2; ++i) {
        bf16x8 v = *(const bf16x8*)(qm + base + qn * 64 + i * 8);
#pragma unroll
        for (int j = 0; j < 8; ++j) qv[i * 8 + j] = (float)v[j];
    }
    float sc[8];
#pragma unroll
    for (int kn = 0; kn < 8; ++kn) {
        float s = 0.f;
#pragma unroll
        for (int i = 0; i < 2; ++i) {
            bf16x8 v = *(const bf16x8*)(km + base + kn * 64 + i * 8);
#pragma unroll
            for (int j = 0; j < 8; ++j) s += qv[i * 8 + j] * (float)v[j];
        }
        sc[kn] = s * 0.25f;
    }
    float mx = sc[0];
#pragma unroll
    for (int kn = 1; kn < 8; ++kn) mx = fmaxf(mx, sc[kn]);
    float ssum = 0.f;
#pragma unroll
    for (int kn = 0; kn < 8; ++kn) { sc[kn] = expf(sc[kn] - mx); ssum += sc[kn]; }
    float inv = 1.f / ssum;

    float acc[16] = {};
#pragma unroll
    for (int kn = 0; kn < 8; ++kn) {
        float w = sc[kn] * inv;
#pragma unroll
        for (int i = 0; i < 2; ++i) {
            bf16x8 v = *(const bf16x8*)(vm + base + kn * 64 + i * 8);
#pragma unroll
            for (int j = 0; j < 8; ++j) acc[i * 8 + j] += w * (float)v[j];
        }
    }
#pragma unroll
    for (int i = 0; i < 2; ++i) {
        bf16x8 o;
#pragma unroll
        for (int j = 0; j < 8; ++j) o[j] = (__bf16)acc[i * 8 + j];
        *(bf16x8*)(omb + base + qn * 64 + i * 8) = o;
    }
}

// ---------------------------------------------------------------------------
// att GEMM: (32768 x 64) om @ fcgT(512x64)^T with fused sig*tanh epilogue.
// ---------------------------------------------------------------------------
__global__ __launch_bounds__(256) void att_gemm(
    const __hip_bfloat16* __restrict__ omb,    // (32768,64)
    const __hip_bfloat16* __restrict__ fcgT,   // (512,64)
    const float* __restrict__ fc_b, const float* __restrict__ gate_b,
    __hip_bfloat16* __restrict__ attb)         // (32768,256) == (B,2048)
{
    const int m0 = blockIdx.y * 128;
    const int n0 = blockIdx.x * 64;
    const int tid = threadIdx.x;
    const int lane = tid & 63, wid = tid >> 6;
    const int wr = wid >> 1, wc = wid & 1;
    const int l15 = lane & 15, l4 = lane >> 4;

    __shared__ __align__(16) char lds_raw[16384 + 8192];
    char* Alds = lds_raw;
    char* Blds = lds_raw + 16384;

    f32x4 acc[4][2] = {};
#pragma unroll
    for (int ii = 0; ii < 4; ++ii) {
        int issue = ii * 4 + wid;
        int chunk = issue * 64 + lane;
        int r = chunk >> 3, cs = chunk & 7;
        int cl = cs ^ (r & 7);
        const __hip_bfloat16* g = omb + (long)(m0 + r) * 64 + cl * 8;
        GLDS16(g, Alds + issue * 1024);
    }
#pragma unroll
    for (int jj = 0; jj < 2; ++jj) {
        int issue = jj * 4 + wid;
        int chunk = issue * 64 + lane;
        int r = chunk >> 3, cs = chunk & 7;
        int cl = cs ^ (r & 7);
        const __hip_bfloat16* g = fcgT + (long)(n0 + r) * 64 + cl * 8;
        GLDS16(g, Blds + issue * 1024);
    }
    __syncthreads();
#pragma unroll
    for (int kk = 0; kk < 2; ++kk) {
        bf16x8 af[4], bfr[2];
#pragma unroll
        for (int im = 0; im < 4; ++im) {
            int r = wr * 64 + im * 16 + l15;
            int cl = (kk * 4 + l4) ^ (l15 & 7);
            af[im] = *(const bf16x8*)(Alds + r * 128 + cl * 16);
        }
#pragma unroll
        for (int jn = 0; jn < 2; ++jn) {
            int r = wc * 32 + jn * 16 + l15;
            int cl = (kk * 4 + l4) ^ (l15 & 7);
            bfr[jn] = *(const bf16x8*)(Blds + r * 128 + cl * 16);
        }
#pragma unroll
        for (int im = 0; im < 4; ++im)
#pragma unroll
            for (int jn = 0; jn < 2; ++jn)
                acc[im][jn] = __builtin_amdgcn_mfma_f32_16x16x32_bf16(
                    af[im], bfr[jn], acc[im][jn], 0, 0, 0);
    }
    const int o = ((n0 + wc * 32) >> 1) + l15;
    const float fb = fc_b[o], gb = gate_b[o];
#pragma unroll
    for (int im = 0; im < 4; ++im)
#pragma unroll
        for (int reg = 0; reg < 4; ++reg) {
            long m = m0 + wr * 64 + im * 16 + l4 * 4 + reg;
            float att = sigmoidf_(acc[im][1][reg] + gb) * tanhf(acc[im][0][reg] + fb);
            attb[m * 256 + o] = __float2bfloat16(att);
        }
}

// ---------------------------------------------------------------------------
// Final elementwise: h2 = hnewb + attb; masked select; mask_w write.
// ---------------------------------------------------------------------------
__global__ __launch_bounds__(256) void final_elem(
    const __hip_bfloat16* __restrict__ hnewb, const __hip_bfloat16* __restrict__ attb,
    const float* __restrict__ maskb,
    const float* __restrict__ hx, const float* __restrict__ cx,
    float* __restrict__ hx_out, float* __restrict__ cx_out, float* __restrict__ mask_w)
{
    long i4 = (long)blockIdx.x * 256 + threadIdx.x;   // 2,097,152 quads
    long e = i4 * 4;
    int n = (int)((e >> 8) & 7);
    long b = e >> 11;
    float mv = maskb[b * 8 + n];
    ushort4 hn = ((const ushort4*)hnewb)[i4];
    ushort4 at = ((const ushort4*)attb)[i4];
    float4 hxv = ((const float4*)hx)[i4];
    float4 cxv = ((const float4*)cx)[i4];
    float4 h2;
    h2.x = b2f_(hn.x) + b2f_(at.x);
    h2.y = b2f_(hn.y) + b2f_(at.y);
    h2.z = b2f_(hn.z) + b2f_(at.z);
    h2.w = b2f_(hn.w) + b2f_(at.w);
    bool k = (mv != 0.f);
    float4 ho = k ? h2 : hxv;
    float4 co = k ? h2 : cxv;
    ((float4*)hx_out)[i4] = ho;
    ((float4*)cx_out)[i4] = co;
    ((float4*)mask_w)[i4] = make_float4(mv, mv, mv, mv);
}

// ---------------------------------------------------------------------------
extern "C" void kernel_launch(void* const* d_in, const int* in_sizes, int n_in,
                              void* d_out, int out_size, void* d_ws, size_t ws_size,
                              hipStream_t stream)
{
    const float* inp     = (const float*)d_in[0];
    const float* hx      = (const float*)d_in[1];
    const float* cx      = (const float*)d_in[2];
    const float* Wq_i    = (const float*)d_in[4];
    const float* Wk_i    = (const float*)d_in[5];
    const float* Wv_i    = (const float*)d_in[6];
    const float* fc_i_w  = (const float*)d_in[7];
    const float* fc_i_b  = (const float*)d_in[8];
    const float* Wq_m    = (const float*)d_in[9];
    const float* Wk_m    = (const float*)d_in[10];
    const float* Wv_m    = (const float*)d_in[11];
    const float* fc_m_w  = (const float*)d_in[12];
    const float* fc_m_b  = (const float*)d_in[13];
    const float* gate_m_w= (const float*)d_in[14];
    const float* gate_m_b= (const float*)d_in[15];
    const float* Wih     = (const float*)d_in[16];
    const float* Whh     = (const float*)d_in[17];
    const float* bih     = (const float*)d_in[18];
    const float* bhh     = (const float*)d_in[19];

    float* out = (float*)d_out;
    const long BH = (long)B_SZ * NHID_;   // 8388608
    float* hx_out = out;
    float* cx_out = out + BH;
    float* mask_w = out + 2 * BH;
    __hip_bfloat16* hxb = (__hip_bfloat16*)out;   // bf16 hx in hx_out region (dead after gru)
    __hip_bfloat16* qkvb = (__hip_bfloat16*)out;  // q|k|v bf16, written post-gru
    float* pbuf = cx_out;                         // (B,2048) f32 p, dead before final_elem

    // Workspace layout (float offsets; all sizes exact):
    float* w = (float*)d_ws;
    float* a_buf = w;                                        // [0, 32768)
    float* maskb = w + 32768;                                // [32768, 65536)
    float* cbuf  = w + 65536;                                // [65536, 71680)
    __hip_bfloat16* fcgT = (__hip_bfloat16*)(w + 73728);     // 32768 bf16   -> [73728, 90112)
    __hip_bfloat16* WmT  = (__hip_bfloat16*)(w + 90112);     // 393216 bf16  -> [90112, 286720)
    __hip_bfloat16* Wihb = (__hip_bfloat16*)(w + 286720);    // 6291456 bf16 -> [286720, 3432448)
    __hip_bfloat16* Whhb = (__hip_bfloat16*)(w + 3432448);   // 1572864 bf16 -> [3432448, 4218880)
    __hip_bfloat16* wfcb = (__hip_bfloat16*)(w + 4218880);   // 4194304 bf16 -> [4218880, 6316032)
    __hip_bfloat16* hnewb= (__hip_bfloat16*)(w + 6316032);   // 8388608 bf16 -> [6316032, 10510336)
    // pre-gru overlays inside hnewb's region (dead before gru writes hnewb):
    float* krow = w + 8413184;                               // [8413184, 8675328)
    __hip_bfloat16* inpb = (__hip_bfloat16*)(w + 8675328);   // 2097152 bf16 -> [8675328, 9723904)
    __hip_bfloat16* WvB  = (__hip_bfloat16*)(w + 9723904);   // 524288 bf16  -> [9723904, 9986048)
    __hip_bfloat16* fcT  = (__hip_bfloat16*)(w + 9986048);   // 1048576 bf16 -> [9986048, 10510336)
    __hip_bfloat16* WvFT = (__hip_bfloat16*)(w + 10510336);  // 524288 bf16  -> [10510336, 10772480)
    // post-gru overlays (Wihb/Whhb/wfcb dead):
    __hip_bfloat16* omb  = (__hip_bfloat16*)(w + 286720);    // 2097152 bf16 -> [286720, 1335296)
    __hip_bfloat16* attb = (__hip_bfloat16*)(w + 1335296);   // 8388608 bf16 -> [1335296, 5529600)

    // ---- Phase A: conversions / prep ----
    wih_prep<<<dim3(6144), dim3(256), 0, stream>>>(Wih, fc_i_b, bih, Wihb, cbuf);
    f2b_kernel<<<dim3(1024), dim3(256), 0, stream>>>(inp, inpb, 524288);
    f2b_kernel<<<dim3(1024), dim3(256), 0, stream>>>(Whh, Whhb, 393216);
    f2b_kernel<<<dim3(512), dim3(256), 0, stream>>>(Wv_i + 512 * 1024, WvB, 131072);
    tconv_kernel<<<dim3(32, 32, 1), dim3(256), 0, stream>>>(fc_i_w, 1024, 0, fcT, 1024, 0);
    tconv_kernel<<<dim3(2, 8, 8), dim3(256), 0, stream>>>(Wq_m, 64, 16384, WmT, 256, 49152);
    tconv_kernel<<<dim3(2, 8, 8), dim3(256), 0, stream>>>(Wk_m, 64, 16384, WmT + 64 * 256, 256, 49152);
    tconv_kernel<<<dim3(2, 8, 8), dim3(256), 0, stream>>>(Wv_m, 64, 16384, WmT + 128 * 256, 256, 49152);
    fcg_prep<<<dim3(128), dim3(256), 0, stream>>>(fc_m_w, gate_m_w, fcgT);
    // ---- Phase B: mask path (fp32, reordered contraction) + hxb emit ----
    gemm_nn<<<dim3(1, 64, 1), dim3(256), 0, stream>>>(
        inp, Wk_i + 512 * 64, krow, 4096, 64, 512, 512, 64, 64, 0, 0, 0);
    gemm_nt_f32<<<dim3(4, 64, 8), dim3(256), 0, stream>>>(
        krow, 64, Wq_i, 64, pbuf, 2048, 64, 16384, 256);
    s1_mask_fused<<<dim3(1024), dim3(256), 0, stream>>>(hx, pbuf, a_buf, maskb, hxb);
    // WvFT(1024x512) = fcT(1024x1024) @ WvB(512x1024)^T
    gemm_mfma_obf16<<<dim3(8, 8, 1), dim3(256), 0, stream>>>(
        fcT, 1024, WvB, 1024, WvFT, 512, 1024);
    // wfcb(4096x1024) = inpb(4096x512) @ WvFT^T
    gemm_mfma_obf16<<<dim3(16, 32, 1), dim3(256), 0, stream>>>(
        inpb, 512, WvFT, 512, wfcb, 1024, 512);
    // ---- Phase C: fused MFMA GEMM + GRU -> hnewb (2-phase dbuf, hoisted) ----
    gru_fused_mfma<<<dim3(2048), dim3(512), 0, stream>>>(
        wfcb, hxb, a_buf, cbuf, Wihb, Whhb, bhh, hnewb);
    // ---- Phase D: q/k/v_m projections (bf16, into hx_out region) ----
    gemm_mfma_qkv<<<dim3(3, 32, 8), dim3(256), 0, stream>>>(hnewb, WmT, qkvb);
    // ---- Phase E: memory attention + att GEMM + final ----
    mattn_kernel<<<dim3(512), dim3(256), 0, stream>>>(
        qkvb, qkvb + 2097152, qkvb + 4194304, omb);
    att_gemm<<<dim3(8, 256, 1), dim3(256), 0, stream>>>(omb, fcgT, fc_m_b, gate_m_b, attb);
    final_elem<<<dim3(8192), dim3(256), 0, stream>>>(
        hnewb, attb, maskb, hx, cx, hx_out, cx_out, mask_w);
}

// Round 12
// 262.692 us; speedup vs baseline: 1.4551x; 1.0280x over previous
//
#include <hip/hip_runtime.h>
#include <hip/hip_bf16.h>

#define B_SZ 4096
#define NHID_ 2048

typedef __bf16 bf16x8 __attribute__((ext_vector_type(8)));
typedef float f32x4 __attribute__((ext_vector_type(4)));

__device__ __forceinline__ float sigmoidf_(float x) { return 1.f / (1.f + expf(-x)); }
__device__ __forceinline__ float b2f_(unsigned short u) {
    unsigned v = (unsigned)u << 16;
    return __builtin_bit_cast(float, v);
}

#define GLDS16(gp, lp) __builtin_amdgcn_global_load_lds( \
    (const __attribute__((address_space(1))) void*)(gp), \
    (__attribute__((address_space(3))) void*)(lp), 16, 0, 0)

// ---------------------------------------------------------------------------
// Merged fp32 -> bf16 conversion for 3 buffers (segment select by index).
// Sizes in float4 quads: inp 524288 | Whh 393216 | WvB 131072 = 1048576.
// ---------------------------------------------------------------------------
__global__ __launch_bounds__(256) void f2b3_kernel(
    const float* __restrict__ s0, __hip_bfloat16* __restrict__ d0,
    const float* __restrict__ s1, __hip_bfloat16* __restrict__ d1,
    const float* __restrict__ s2, __hip_bfloat16* __restrict__ d2)
{
    long i = (long)blockIdx.x * 256 + threadIdx.x;   // 1,048,576 quads
    const float* src; __hip_bfloat16* dst; long off;
    if (i < 524288)       { src = s0; dst = d0; off = i; }
    else if (i < 917504)  { src = s1; dst = d1; off = i - 524288; }
    else                  { src = s2; dst = d2; off = i - 917504; }
    float4 v = ((const float4*)src)[off];
    __hip_bfloat16 b0 = __float2bfloat16(v.x);
    __hip_bfloat16 b1 = __float2bfloat16(v.y);
    __hip_bfloat16 b2 = __float2bfloat16(v.z);
    __hip_bfloat16 b3 = __float2bfloat16(v.w);
    ushort4 u;
    u.x = *(unsigned short*)&b0; u.y = *(unsigned short*)&b1;
    u.z = *(unsigned short*)&b2; u.w = *(unsigned short*)&b3;
    ((ushort4*)dst)[off] = u;
}

// ---------------------------------------------------------------------------
// Wih convert + cb: Wihb = bf16(Wih); cb[j] = dot(fc_i_b, Wih[j,:]) + bih[j]
// ---------------------------------------------------------------------------
__global__ __launch_bounds__(256) void wih_prep(
    const float* __restrict__ Wih, const float* __restrict__ fc_i_b,
    const float* __restrict__ bih, __hip_bfloat16* __restrict__ Wihb,
    float* __restrict__ cb)
{
    long j = blockIdx.x;
    const float* row = Wih + j * 1024;
    __hip_bfloat16* drow = Wihb + j * 1024;
    int i = threadIdx.x * 4;
    float4 v = *(const float4*)(row + i);
    __hip_bfloat16 b0 = __float2bfloat16(v.x);
    __hip_bfloat16 b1 = __float2bfloat16(v.y);
    __hip_bfloat16 b2 = __float2bfloat16(v.z);
    __hip_bfloat16 b3 = __float2bfloat16(v.w);
    ushort4 u;
    u.x = *(unsigned short*)&b0; u.y = *(unsigned short*)&b1;
    u.z = *(unsigned short*)&b2; u.w = *(unsigned short*)&b3;
    *(ushort4*)(drow + i) = u;
    float s = fc_i_b[i] * v.x + fc_i_b[i + 1] * v.y +
              fc_i_b[i + 2] * v.z + fc_i_b[i + 3] * v.w;
#pragma unroll
    for (int off = 32; off > 0; off >>= 1) s += __shfl_xor(s, off, 64);
    __shared__ float red[4];
    if ((threadIdx.x & 63) == 0) red[threadIdx.x >> 6] = s;
    __syncthreads();
    if (threadIdx.x == 0) cb[j] = red[0] + red[1] + red[2] + red[3] + bih[j];
}

// ---------------------------------------------------------------------------
// Transpose + convert: dst[c*ldd + r] (bf16) = src[r*C + c] (f32), batched z.
// ---------------------------------------------------------------------------
__global__ __launch_bounds__(256) void tconv_kernel(
    const float* __restrict__ src, int C, long sS,
    __hip_bfloat16* __restrict__ dst, int ldd, long sD)
{
    src += (long)blockIdx.z * sS;
    dst += (long)blockIdx.z * sD;
    const int r0 = blockIdx.y * 32, c0 = blockIdx.x * 32;
    const int tx = threadIdx.x & 31, ty = threadIdx.x >> 5;
    __shared__ float tile[32][33];
#pragma unroll
    for (int i = 0; i < 4; ++i)
        tile[ty + i * 8][tx] = src[(long)(r0 + ty + i * 8) * C + c0 + tx];
    __syncthreads();
#pragma unroll
    for (int i = 0; i < 4; ++i)
        dst[(long)(c0 + ty + i * 8) * ldd + r0 + tx] = __float2bfloat16(tile[tx][ty + i * 8]);
}

// ---------------------------------------------------------------------------
// Merged WmT transpose: z in [0,24); src = {Wq_m,Wk_m,Wv_m}[z>>3], batch z&7.
// Each (8,256,64) -> WmT[(z&7)][ (z>>3)*64 .. +64 ][256].
// ---------------------------------------------------------------------------
__global__ __launch_bounds__(256) void tconv_wm(
    const float* __restrict__ Wq, const float* __restrict__ Wk,
    const float* __restrict__ Wv, __hip_bfloat16* __restrict__ WmT)
{
    const int z = blockIdx.z;
    const int which = z >> 3, nb = z & 7;
    const float* src = (which == 0) ? Wq : (which == 1) ? Wk : Wv;
    src += (long)nb * 16384;                       // (256,64) slab
    __hip_bfloat16* dst = WmT + (long)nb * 49152 + which * 64 * 256;
    const int r0 = blockIdx.y * 32, c0 = blockIdx.x * 32;
    const int tx = threadIdx.x & 31, ty = threadIdx.x >> 5;
    __shared__ float tile[32][33];
#pragma unroll
    for (int i = 0; i < 4; ++i)
        tile[ty + i * 8][tx] = src[(long)(r0 + ty + i * 8) * 64 + c0 + tx];
    __syncthreads();
#pragma unroll
    for (int i = 0; i < 4; ++i)
        dst[(long)(c0 + ty + i * 8) * 256 + r0 + tx] = __float2bfloat16(tile[tx][ty + i * 8]);
}

// ---------------------------------------------------------------------------
// Build fcgT (512 x 64)
// ---------------------------------------------------------------------------
__global__ __launch_bounds__(256) void fcg_prep(
    const float* __restrict__ fc_w, const float* __restrict__ gate_w,
    __hip_bfloat16* __restrict__ fcgT)
{
    int tid = blockIdx.x * 256 + threadIdx.x;  // 32768
    int np = tid >> 6, k = tid & 63;
    int o = (np >> 5) * 16 + (np & 15);
    const float* src = ((np >> 4) & 1) ? gate_w : fc_w;
    fcgT[tid] = __float2bfloat16(src[k * 256 + o]);
}

// ---------------------------------------------------------------------------
// Generic fp32 tiled GEMM (krow only)
// ---------------------------------------------------------------------------
#define GM_BM 64
#define GM_BN 64
#define GM_BK 16

__global__ __launch_bounds__(256) void gemm_nn(
    const float* __restrict__ A, const float* __restrict__ Bm, float* __restrict__ C,
    int M, int N, int K, int lda, int ldb, int ldc,
    long sA, long sB, long sC)
{
    const int z = blockIdx.z;
    A += (long)z * sA; Bm += (long)z * sB; C += (long)z * sC;
    const int m0 = blockIdx.y * GM_BM;
    const int n0 = blockIdx.x * GM_BN;
    const int tid = threadIdx.x;
    const int tx = tid & 15;
    const int ty = tid >> 4;

    __shared__ float As[GM_BK][GM_BM + 4];
    __shared__ float Bs[GM_BK][GM_BN + 4];

    float acc[4][4] = {};

    for (int k0 = 0; k0 < K; k0 += GM_BK) {
#pragma unroll
        for (int i = 0; i < 4; ++i) {
            int idx = tid + i * 256;
            int r = idx >> 4, c = idx & 15;
            As[c][r] = A[(long)(m0 + r) * lda + k0 + c];
        }
#pragma unroll
        for (int i = 0; i < 4; ++i) {
            int idx = tid + i * 256;
            int r = idx >> 6, c = idx & 63;
            Bs[r][c] = Bm[(long)(k0 + r) * ldb + n0 + c];
        }
        __syncthreads();
#pragma unroll
        for (int kk = 0; kk < GM_BK; ++kk) {
            float4 a4 = *(const float4*)&As[kk][ty * 4];
            float4 b4 = *(const float4*)&Bs[kk][tx * 4];
            float av[4] = {a4.x, a4.y, a4.z, a4.w};
            float bv[4] = {b4.x, b4.y, b4.z, b4.w};
#pragma unroll
            for (int i = 0; i < 4; ++i)
#pragma unroll
                for (int j = 0; j < 4; ++j)
                    acc[i][j] += av[i] * bv[j];
        }
        __syncthreads();
    }
#pragma unroll
    for (int i = 0; i < 4; ++i) {
        long m = m0 + ty * 4 + i;
#pragma unroll
        for (int j = 0; j < 4; ++j) {
            int n = n0 + tx * 4 + j;
            C[m * ldc + n] = acc[i][j];
        }
    }
}

// ---------------------------------------------------------------------------
// fp32 GEMM with N-major B: C(MxN) = A(MxK) @ BT(NxK)^T, batched z over BT/C.
// ---------------------------------------------------------------------------
__global__ __launch_bounds__(256) void gemm_nt_f32(
    const float* __restrict__ A, int lda,
    const float* __restrict__ BT, int ldb,
    float* __restrict__ C, int ldc, int K, long sB, long sC)
{
    BT += (long)blockIdx.z * sB;
    C  += (long)blockIdx.z * sC;
    const int m0 = blockIdx.y * 64;
    const int n0 = blockIdx.x * 64;
    const int tid = threadIdx.x;
    const int tx = tid & 15;
    const int ty = tid >> 4;

    __shared__ float As[16][68];
    __shared__ float Bs[64][17];

    float acc[4][4] = {};

    for (int k0 = 0; k0 < K; k0 += 16) {
#pragma unroll
        for (int i = 0; i < 4; ++i) {
            int idx = tid + i * 256;
            int r = idx >> 4, c = idx & 15;
            As[c][r] = A[(long)(m0 + r) * lda + k0 + c];
        }
#pragma unroll
        for (int i = 0; i < 4; ++i) {
            int idx = tid + i * 256;
            int r = idx >> 4, c = idx & 15;
            Bs[r][c] = BT[(long)(n0 + r) * ldb + k0 + c];
        }
        __syncthreads();
#pragma unroll
        for (int kk = 0; kk < 16; ++kk) {
            float4 a4 = *(const float4*)&As[kk][ty * 4];
            float av[4] = {a4.x, a4.y, a4.z, a4.w};
            float bv[4];
#pragma unroll
            for (int j = 0; j < 4; ++j) bv[j] = Bs[tx * 4 + j][kk];
#pragma unroll
            for (int i = 0; i < 4; ++i)
#pragma unroll
                for (int j = 0; j < 4; ++j)
                    acc[i][j] += av[i] * bv[j];
        }
        __syncthreads();
    }
#pragma unroll
    for (int i = 0; i < 4; ++i) {
        long m = m0 + ty * 4 + i;
#pragma unroll
        for (int j = 0; j < 4; ++j) {
            int n = n0 + tx * 4 + j;
            C[m * ldc + n] = acc[i][j];
        }
    }
}

// ---------------------------------------------------------------------------
// Fused s1 / sigmoid / top-k mask + hx->bf16 emit.
// ---------------------------------------------------------------------------
__global__ __launch_bounds__(256) void s1_mask_fused(
    const float* __restrict__ hx,   // (B,2048)
    const float* __restrict__ p,    // (B,2048)  p[b, n*256+i]
    float* __restrict__ a_buf, float* __restrict__ mask_buf,
    __hip_bfloat16* __restrict__ hxb)   // (B,2048) bf16 out
{
    const int wave = threadIdx.x >> 6;
    const int lane = threadIdx.x & 63;
    const long b = (long)blockIdx.x * 4 + wave;
    const long base = b * 2048 + lane * 4;
    float s1v[8];
#pragma unroll
    for (int n = 0; n < 8; ++n) {
        float4 hv = *(const float4*)(hx + base + n * 256);
        float4 pv = *(const float4*)(p + base + n * 256);
        __hip_bfloat16 c0 = __float2bfloat16(hv.x);
        __hip_bfloat16 c1 = __float2bfloat16(hv.y);
        __hip_bfloat16 c2 = __float2bfloat16(hv.z);
        __hip_bfloat16 c3 = __float2bfloat16(hv.w);
        ushort4 u;
        u.x = *(unsigned short*)&c0; u.y = *(unsigned short*)&c1;
        u.z = *(unsigned short*)&c2; u.w = *(unsigned short*)&c3;
        *(ushort4*)(hxb + base + n * 256) = u;
        float s = hv.x * pv.x + hv.y * pv.y + hv.z * pv.z + hv.w * pv.w;
#pragma unroll
        for (int off = 32; off > 0; off >>= 1) s += __shfl_xor(s, off, 64);
        s1v[n] = s * 0.125f;
    }
    unsigned maskbits = 0;
#pragma unroll
    for (int n = 0; n < 8; ++n) {
        int rank = 0;
#pragma unroll
        for (int m = 0; m < 8; ++m) {
            if (m == n) continue;
            if (s1v[m] < s1v[n] || (s1v[m] == s1v[n] && m < n)) rank++;
        }
        if (rank >= 4) maskbits |= (1u << n);
    }
    if (lane < 8) {
        float sv = s1v[0];
#pragma unroll
        for (int n = 1; n < 8; ++n)
            if (lane == n) sv = s1v[n];
        a_buf[b * 8 + lane] = sigmoidf_(sv);
        mask_buf[b * 8 + lane] = ((maskbits >> lane) & 1u) ? 1.0f : 0.0f;
    }
}

// ---------------------------------------------------------------------------
// MFMA GEMM: C(bf16, MxN) = A(bf16, MxK, lda) @ BT(bf16, NxK, ldb)^T
// ---------------------------------------------------------------------------
__global__ __launch_bounds__(256) void gemm_mfma_obf16(
    const __hip_bfloat16* __restrict__ A, int lda,
    const __hip_bfloat16* __restrict__ BT, int ldb,
    __hip_bfloat16* __restrict__ C, int ldc, int K)
{
    const int m0 = blockIdx.y * 128;
    const int n0 = blockIdx.x * 64;
    const int tid = threadIdx.x;
    const int lane = tid & 63, wid = tid >> 6;
    const int wr = wid >> 1, wc = wid & 1;
    const int l15 = lane & 15, l4 = lane >> 4;

    __shared__ __align__(16) char lds_raw[16384 + 8192];
    char* Alds = lds_raw;
    char* Blds = lds_raw + 16384;

    f32x4 acc[4][2] = {};

    for (int k0 = 0; k0 < K; k0 += 64) {
#pragma unroll
        for (int ii = 0; ii < 4; ++ii) {
            int issue = ii * 4 + wid;
            int chunk = issue * 64 + lane;
            int r = chunk >> 3, cs = chunk & 7;
            int cl = cs ^ (r & 7);
            const __hip_bfloat16* g = A + (long)(m0 + r) * lda + k0 + cl * 8;
            GLDS16(g, Alds + issue * 1024);
        }
#pragma unroll
        for (int jj = 0; jj < 2; ++jj) {
            int issue = jj * 4 + wid;
            int chunk = issue * 64 + lane;
            int r = chunk >> 3, cs = chunk & 7;
            int cl = cs ^ (r & 7);
            const __hip_bfloat16* g = BT + (long)(n0 + r) * ldb + k0 + cl * 8;
            GLDS16(g, Blds + issue * 1024);
        }
        __syncthreads();
#pragma unroll
        for (int kk = 0; kk < 2; ++kk) {
            bf16x8 af[4], bfr[2];
#pragma unroll
            for (int im = 0; im < 4; ++im) {
                int r = wr * 64 + im * 16 + l15;
                int cl = (kk * 4 + l4) ^ (l15 & 7);
                af[im] = *(const bf16x8*)(Alds + r * 128 + cl * 16);
            }
#pragma unroll
            for (int jn = 0; jn < 2; ++jn) {
                int r = wc * 32 + jn * 16 + l15;
                int cl = (kk * 4 + l4) ^ (l15 & 7);
                bfr[jn] = *(const bf16x8*)(Blds + r * 128 + cl * 16);
            }
#pragma unroll
            for (int im = 0; im < 4; ++im)
#pragma unroll
                for (int jn = 0; jn < 2; ++jn)
                    acc[im][jn] = __builtin_amdgcn_mfma_f32_16x16x32_bf16(
                        af[im], bfr[jn], acc[im][jn], 0, 0, 0);
        }
        __syncthreads();
    }
#pragma unroll
    for (int im = 0; im < 4; ++im)
#pragma unroll
        for (int reg = 0; reg < 4; ++reg) {
            long m = m0 + wr * 64 + im * 16 + l4 * 4 + reg;
#pragma unroll
            for (int jn = 0; jn < 2; ++jn) {
                int n = n0 + wc * 32 + jn * 16 + l15;
                C[m * ldc + n] = __float2bfloat16(acc[im][jn][reg]);
            }
        }
}

// ---------------------------------------------------------------------------
// Fused q/k/v_m projections (bf16 out).
// ---------------------------------------------------------------------------
__global__ __launch_bounds__(256) void gemm_mfma_qkv(
    const __hip_bfloat16* __restrict__ hnewb,  // (B,2048)
    const __hip_bfloat16* __restrict__ WmT,    // (8,192,256)
    __hip_bfloat16* __restrict__ qout)         // q|k|v, each 2097152 bf16
{
    const int z = blockIdx.z;
    const int m0 = blockIdx.y * 128;
    const int n0 = blockIdx.x * 64;
    const int tid = threadIdx.x;
    const int lane = tid & 63, wid = tid >> 6;
    const int wr = wid >> 1, wc = wid & 1;
    const int l15 = lane & 15, l4 = lane >> 4;

    const __hip_bfloat16* A = hnewb + z * 256;
    const __hip_bfloat16* BT = WmT + (long)z * 192 * 256;

    __shared__ __align__(16) char lds_raw[16384 + 8192];
    char* Alds = lds_raw;
    char* Blds = lds_raw + 16384;

    f32x4 acc[4][2] = {};

    for (int k0 = 0; k0 < 256; k0 += 64) {
#pragma unroll
        for (int ii = 0; ii < 4; ++ii) {
            int issue = ii * 4 + wid;
            int chunk = issue * 64 + lane;
            int r = chunk >> 3, cs = chunk & 7;
            int cl = cs ^ (r & 7);
            const __hip_bfloat16* g = A + (long)(m0 + r) * 2048 + k0 + cl * 8;
            GLDS16(g, Alds + issue * 1024);
        }
#pragma unroll
        for (int jj = 0; jj < 2; ++jj) {
            int issue = jj * 4 + wid;
            int chunk = issue * 64 + lane;
            int r = chunk >> 3, cs = chunk & 7;
            int cl = cs ^ (r & 7);
            const __hip_bfloat16* g = BT + (long)(n0 + r) * 256 + k0 + cl * 8;
            GLDS16(g, Blds + issue * 1024);
        }
        __syncthreads();
#pragma unroll
        for (int kk = 0; kk < 2; ++kk) {
            bf16x8 af[4], bfr[2];
#pragma unroll
            for (int im = 0; im < 4; ++im) {
                int r = wr * 64 + im * 16 + l15;
                int cl = (kk * 4 + l4) ^ (l15 & 7);
                af[im] = *(const bf16x8*)(Alds + r * 128 + cl * 16);
            }
#pragma unroll
            for (int jn = 0; jn < 2; ++jn) {
                int r = wc * 32 + jn * 16 + l15;
                int cl = (kk * 4 + l4) ^ (l15 & 7);
                bfr[jn] = *(const bf16x8*)(Blds + r * 128 + cl * 16);
            }
#pragma unroll
            for (int im = 0; im < 4; ++im)
#pragma unroll
                for (int jn = 0; jn < 2; ++jn)
                    acc[im][jn] = __builtin_amdgcn_mfma_f32_16x16x32_bf16(
                        af[im], bfr[jn], acc[im][jn], 0, 0, 0);
        }
        __syncthreads();
    }
#pragma unroll
    for (int jn = 0; jn < 2; ++jn) {
        int j = n0 + wc * 32 + jn * 16 + l15;   // [0,192)
        int g = j >> 6, d = j & 63;
        __hip_bfloat16* outp = qout + (long)g * 2097152 + (long)z * 64 + d;
#pragma unroll
        for (int im = 0; im < 4; ++im)
#pragma unroll
            for (int reg = 0; reg < 4; ++reg) {
                long m = m0 + wr * 64 + im * 16 + l4 * 4 + reg;
                outp[m * 512] = __float2bfloat16(acc[im][jn][reg]);
            }
    }
}

// ---------------------------------------------------------------------------
// MFMA big GEMM + fused GRU epilogue — 2-phase dbuf, hoisted addressing
// (identical to R11-verified).
// ---------------------------------------------------------------------------
__global__ __launch_bounds__(512) void gru_fused_mfma(
    const __hip_bfloat16* __restrict__ wfcb,   // (B,1024)
    const __hip_bfloat16* __restrict__ hxb,    // (B,2048)
    const float* __restrict__ a_buf,           // (B,8)
    const float* __restrict__ cb,              // (8,768)
    const __hip_bfloat16* __restrict__ Wihb,   // (8,768,1024)
    const __hip_bfloat16* __restrict__ Whhb,   // (8,768,256)
    const float* __restrict__ bhh,             // (8,768)
    __hip_bfloat16* __restrict__ hnewb)        // (B,2048)
{
    const int bid = blockIdx.x;
    const int kblk = bid & 7;
    const int r_ = bid >> 3;
    const int ol0 = (r_ & 7) * 32;
    const int m0 = (r_ >> 3) * 128;
    const int tid = threadIdx.x;
    const int lane = tid & 63, wid = tid >> 6;
    const int wr = wid >> 1;
    const int wc = wid & 1;
    const int l15 = lane & 15, l4 = lane >> 4;

    __shared__ __align__(16) char lds_raw[2 * 28672];

    f32x4 accx[2][3] = {};
    f32x4 acch[2][3] = {};

    const __hip_bfloat16* Wk = Wihb + (long)kblk * 768 * 1024;
    const __hip_bfloat16* Wh = Whhb + (long)kblk * 768 * 256;
    const __hip_bfloat16* hxk = hxb + kblk * 256;

    const int iiA0 = wid, iiA1 = wid + 8;
    const int cA0 = iiA0 * 64 + lane, rA0 = cA0 >> 3, clA0 = (cA0 & 7) ^ (rA0 & 7);
    const int cA1 = iiA1 * 64 + lane, rA1 = cA1 >> 3, clA1 = (cA1 & 7) ^ (rA1 & 7);
    const int jjB0 = wid, jjB1 = wid + 8;
    const int cB0 = jjB0 * 64 + lane, rB0 = cB0 >> 3, clB0 = (cB0 & 7) ^ (rB0 & 7);
    const int cB1 = jjB1 * 64 + lane, rB1 = cB1 >> 3, clB1 = (cB1 & 7) ^ (rB1 & 7);
    const bool hasB1 = (wid < 4);
    const int gg0 = rB0 >> 5, oll0 = rB0 & 31;
    const int gg1 = (rB1 >> 5) & 3, oll1 = rB1 & 31;
    const int dA0 = iiA0 * 1024, dA1 = iiA1 * 1024;
    const int dB0 = 16384 + jjB0 * 1024, dB1 = 16384 + jjB1 * 1024;

    const __hip_bfloat16* pA0 = wfcb + (long)(m0 + rA0) * 1024 + clA0 * 8;
    const __hip_bfloat16* pA1 = wfcb + (long)(m0 + rA1) * 1024 + clA1 * 8;
    const __hip_bfloat16* pB0 = Wk + (long)(gg0 * 256 + ol0 + oll0) * 1024 + clB0 * 8;
    const __hip_bfloat16* pB1 = Wk + (long)(gg1 * 256 + ol0 + oll1) * 1024 + clB1 * 8;

#define STAGE4(buf) do {                                                       \
    char* L = lds_raw + (buf) * 28672;                                         \
    GLDS16(pA0, L + dA0);                                                      \
    GLDS16(pA1, L + dA1);                                                      \
    GLDS16(pB0, L + dB0);                                                      \
    if (hasB1) GLDS16(pB1, L + dB1);                                           \
    pA0 += 64; pA1 += 64; pB0 += 64; pB1 += 64;                                \
} while (0)

    int offA[2][2], offB[2][3];
#pragma unroll
    for (int kk = 0; kk < 2; ++kk) {
        int cl = (kk * 4 + l4) ^ (l15 & 7);
#pragma unroll
        for (int im = 0; im < 2; ++im)
            offA[kk][im] = (wr * 32 + im * 16 + l15) * 128 + cl * 16;
#pragma unroll
        for (int g = 0; g < 3; ++g)
            offB[kk][g] = 16384 + (g * 32 + wc * 16 + l15) * 128 + cl * 16;
    }

#define COMPUTE(acc, buf) do {                                                 \
    char* L = lds_raw + (buf) * 28672;                                         \
    _Pragma("unroll") for (int kk = 0; kk < 2; ++kk) {                         \
        bf16x8 af[2], bfr[3];                                                  \
        _Pragma("unroll") for (int im = 0; im < 2; ++im)                       \
            af[im] = *(const bf16x8*)(L + offA[kk][im]);                       \
        _Pragma("unroll") for (int g = 0; g < 3; ++g)                          \
            bfr[g] = *(const bf16x8*)(L + offB[kk][g]);                        \
        _Pragma("unroll") for (int im = 0; im < 2; ++im)                       \
            _Pragma("unroll") for (int g = 0; g < 3; ++g)                      \
                acc[im][g] = __builtin_amdgcn_mfma_f32_16x16x32_bf16(          \
                    af[im], bfr[g], acc[im][g], 0, 0, 0);                      \
    }                                                                          \
} while (0)

    STAGE4(0);
    asm volatile("s_waitcnt vmcnt(0)" ::: "memory");
    __syncthreads();

    int cur = 0;
    for (int t = 0; t < 16; ++t) {
        if (t < 15) {
            STAGE4(cur ^ 1);
        } else {
            pA0 = hxk + (long)(m0 + rA0) * 2048 + clA0 * 8;
            pA1 = hxk + (long)(m0 + rA1) * 2048 + clA1 * 8;
            pB0 = Wh + (long)(gg0 * 256 + ol0 + oll0) * 256 + clB0 * 8;
            pB1 = Wh + (long)(gg1 * 256 + ol0 + oll1) * 256 + clB1 * 8;
            STAGE4(cur ^ 1);
        }
        __builtin_amdgcn_s_setprio(1);
        COMPUTE(accx, cur);
        __builtin_amdgcn_s_setprio(0);
        asm volatile("s_waitcnt vmcnt(0)" ::: "memory");
        __syncthreads();
        cur ^= 1;
    }
    for (int t = 0; t < 4; ++t) {
        if (t < 3) STAGE4(cur ^ 1);
        __builtin_amdgcn_s_setprio(1);
        COMPUTE(acch, cur);
        __builtin_amdgcn_s_setprio(0);
        asm volatile("s_waitcnt vmcnt(0)" ::: "memory");
        __syncthreads();
        cur ^= 1;
    }
#undef STAGE4
#undef COMPUTE

    const int ol = ol0 + wc * 16 + l15;
    const float* cbk = cb + kblk * 768;
    const float cb0 = cbk[ol], cb1 = cbk[256 + ol], cb2 = cbk[512 + ol];
    const float* bhk = bhh + kblk * 768;
    const float bh0 = bhk[ol], bh1 = bhk[256 + ol], bh2 = bhk[512 + ol];
#pragma unroll
    for (int im = 0; im < 2; ++im) {
#pragma unroll
        for (int reg = 0; reg < 4; ++reg) {
            long m = m0 + wr * 32 + im * 16 + l4 * 4 + reg;
            float av = a_buf[m * 8 + kblk];
            float gx0 = av * accx[im][0][reg] + cb0;
            float gx1 = av * accx[im][1][reg] + cb1;
            float gx2 = av * accx[im][2][reg] + cb2;
            float gh0 = acch[im][0][reg] + bh0;
            float gh1 = acch[im][1][reg] + bh1;
            float gh2 = acch[im][2][reg] + bh2;
            float rr = sigmoidf_(gx0 + gh0);
            float zz = sigmoidf_(gx1 + gh1);
            float nn = tanhf(gx2 + rr * gh2);
            long idx = m * 2048 + kblk * 256 + ol;
            float hxv = __bfloat162float(hxb[idx]);
            hnewb[idx] = __float2bfloat16((1.f - zz) * nn + zz * hxv);
        }
    }
}

// ---------------------------------------------------------------------------
// Memory attention (bf16 in/out)
// ---------------------------------------------------------------------------
__global__ __launch_bounds__(256) void mattn_kernel(
    const __hip_bfloat16* __restrict__ qm, const __hip_bfloat16* __restrict__ km,
    const __hip_bfloat16* __restrict__ vm, __hip_bfloat16* __restrict__ omb)
{
    const int t = threadIdx.x;
    const int local = t & 31;
    const long b = (long)blockIdx.x * 8 + (t >> 5);
    const int h = local >> 3, qn = local & 7;
    const long base = b * 512 + h * 16;

    float qv[16];
#pragma unroll
    for (int i = 0; i < 2; ++i) {
        bf16x8 v = *(const bf16x8*)(qm + base + qn * 64 + i * 8);
#pragma unroll
        for (int j = 0; j < 8; ++j) qv[i * 8 + j] = (float)v[j];
    }
    float sc[8];
#pragma unroll
    for (int kn = 0; kn < 8; ++kn) {
        float s = 0.f;
#pragma unroll
        for (int i = 0; i < 2; ++i) {
            bf16x8 v = *(const bf16x8*)(km + base + kn * 64 + i * 8);
#pragma unroll
            for (int j = 0; j < 8; ++j) s += qv[i * 8 + j] * (float)v[j];
        }
        sc[kn] = s * 0.25f;
    }
    float mx = sc[0];
#pragma unroll
    for (int kn = 1; kn < 8; ++kn) mx = fmaxf(mx, sc[kn]);
    float ssum = 0.f;
#pragma unroll
    for (int kn = 0; kn < 8; ++kn) { sc[kn] = expf(sc[kn] - mx); ssum += sc[kn]; }
    float inv = 1.f / ssum;

    float acc[16] = {};
#pragma unroll
    for (int kn = 0; kn < 8; ++kn) {
        float w = sc[kn] * inv;
#pragma unroll
        for (int i = 0; i < 2; ++i) {
            bf16x8 v = *(const bf16x8*)(vm + base + kn * 64 + i * 8);
#pragma unroll
            for (int j = 0; j < 8; ++j) acc[i * 8 + j] += w * (float)v[j];
        }
    }
#pragma unroll
    for (int i = 0; i < 2; ++i) {
        bf16x8 o;
#pragma unroll
        for (int j = 0; j < 8; ++j) o[j] = (__bf16)acc[i * 8 + j];
        *(bf16x8*)(omb + base + qn * 64 + i * 8) = o;
    }
}

// ---------------------------------------------------------------------------
// Fused att GEMM + final: att = sig(om@gate+gb)*tanh(om@fc+fb);
// h2 = hnewb + att; masked select into hx_out/cx_out; mask_w = mv.
// Row m = b*8+nb (32768 rows); idx = m*256 + o; mv = maskb[m].
// ---------------------------------------------------------------------------
__global__ __launch_bounds__(256) void att_final(
    const __hip_bfloat16* __restrict__ omb,    // (32768,64)
    const __hip_bfloat16* __restrict__ fcgT,   // (512,64)
    const float* __restrict__ fc_b, const float* __restrict__ gate_b,
    const __hip_bfloat16* __restrict__ hnewb,  // (B,2048) == (32768,256)
    const float* __restrict__ maskb,           // (B,8) == (32768)
    const float* __restrict__ hx, const float* __restrict__ cx,
    float* __restrict__ hx_out, float* __restrict__ cx_out,
    float* __restrict__ mask_w)
{
    const int m0 = blockIdx.y * 128;
    const int n0 = blockIdx.x * 64;
    const int tid = threadIdx.x;
    const int lane = tid & 63, wid = tid >> 6;
    const int wr = wid >> 1, wc = wid & 1;
    const int l15 = lane & 15, l4 = lane >> 4;

    __shared__ __align__(16) char lds_raw[16384 + 8192];
    char* Alds = lds_raw;
    char* Blds = lds_raw + 16384;

    f32x4 acc[4][2] = {};
#pragma unroll
    for (int ii = 0; ii < 4; ++ii) {
        int issue = ii * 4 + wid;
        int chunk = issue * 64 + lane;
        int r = chunk >> 3, cs = chunk & 7;
        int cl = cs ^ (r & 7);
        const __hip_bfloat16* g = omb + (long)(m0 + r) * 64 + cl * 8;
        GLDS16(g, Alds + issue * 1024);
    }
#pragma unroll
    for (int jj = 0; jj < 2; ++jj) {
        int issue = jj * 4 + wid;
        int chunk = issue * 64 + lane;
        int r = chunk >> 3, cs = chunk & 7;
        int cl = cs ^ (r & 7);
        const __hip_bfloat16* g = fcgT + (long)(n0 + r) * 64 + cl * 8;
        GLDS16(g, Blds + issue * 1024);
    }
    __syncthreads();
#pragma unroll
    for (int kk = 0; kk < 2; ++kk) {
        bf16x8 af[4], bfr[2];
#pragma unroll
        for (int im = 0; im < 4; ++im) {
            int r = wr * 64 + im * 16 + l15;
            int cl = (kk * 4 + l4) ^ (l15 & 7);
            af[im] = *(const bf16x8*)(Alds + r * 128 + cl * 16);
        }
#pragma unroll
        for (int jn = 0; jn < 2; ++jn) {
            int r = wc * 32 + jn * 16 + l15;
            int cl = (kk * 4 + l4) ^ (l15 & 7);
            bfr[jn] = *(const bf16x8*)(Blds + r * 128 + cl * 16);
        }
#pragma unroll
        for (int im = 0; im < 4; ++im)
#pragma unroll
            for (int jn = 0; jn < 2; ++jn)
                acc[im][jn] = __builtin_amdgcn_mfma_f32_16x16x32_bf16(
                    af[im], bfr[jn], acc[im][jn], 0, 0, 0);
    }
    const int o = ((n0 + wc * 32) >> 1) + l15;
    const float fb = fc_b[o], gb = gate_b[o];
#pragma unroll
    for (int im = 0; im < 4; ++im)
#pragma unroll
        for (int reg = 0; reg < 4; ++reg) {
            long m = m0 + wr * 64 + im * 16 + l4 * 4 + reg;
            long idx = m * 256 + o;
            float mv = maskb[m];
            float att = sigmoidf_(acc[im][1][reg] + gb) * tanhf(acc[im][0][reg] + fb);
            float ho, co;
            if (mv != 0.f) {
                float h2 = __bfloat162float(hnewb[idx]) + att;
                ho = h2; co = h2;
            } else {
                ho = hx[idx]; co = cx[idx];
            }
            hx_out[idx] = ho;
            cx_out[idx] = co;
            mask_w[idx] = mv;
        }
}

// ---------------------------------------------------------------------------
extern "C" void kernel_launch(void* const* d_in, const int* in_sizes, int n_in,
                              void* d_out, int out_size, void* d_ws, size_t ws_size,
                              hipStream_t stream)
{
    const float* inp     = (const float*)d_in[0];
    const float* hx      = (const float*)d_in[1];
    const float* cx      = (const float*)d_in[2];
    const float* Wq_i    = (const float*)d_in[4];
    const float* Wk_i    = (const float*)d_in[5];
    const float* Wv_i    = (const float*)d_in[6];
    const float* fc_i_w  = (const float*)d_in[7];
    const float* fc_i_b  = (const float*)d_in[8];
    const float* Wq_m    = (const float*)d_in[9];
    const float* Wk_m    = (const float*)d_in[10];
    const float* Wv_m    = (const float*)d_in[11];
    const float* fc_m_w  = (const float*)d_in[12];
    const float* fc_m_b  = (const float*)d_in[13];
    const float* gate_m_w= (const float*)d_in[14];
    const float* gate_m_b= (const float*)d_in[15];
    const float* Wih     = (const float*)d_in[16];
    const float* Whh     = (const float*)d_in[17];
    const float* bih     = (const float*)d_in[18];
    const float* bhh     = (const float*)d_in[19];

    float* out = (float*)d_out;
    const long BH = (long)B_SZ * NHID_;   // 8388608
    float* hx_out = out;
    float* cx_out = out + BH;
    float* mask_w = out + 2 * BH;
    __hip_bfloat16* hxb = (__hip_bfloat16*)out;   // bf16 hx in hx_out region (dead after gru)
    __hip_bfloat16* qkvb = (__hip_bfloat16*)out;  // q|k|v bf16, written post-gru (dead after mattn)
    float* pbuf = cx_out;                         // (B,2048) f32 p, dead before att_final

    // Workspace layout (float offsets; all sizes exact):
    float* w = (float*)d_ws;
    float* a_buf = w;                                        // [0, 32768)
    float* maskb = w + 32768;                                // [32768, 65536)
    float* cbuf  = w + 65536;                                // [65536, 71680)
    __hip_bfloat16* fcgT = (__hip_bfloat16*)(w + 73728);     // 32768 bf16   -> [73728, 90112)
    __hip_bfloat16* WmT  = (__hip_bfloat16*)(w + 90112);     // 393216 bf16  -> [90112, 286720)
    __hip_bfloat16* Wihb = (__hip_bfloat16*)(w + 286720);    // 6291456 bf16 -> [286720, 3432448)
    __hip_bfloat16* Whhb = (__hip_bfloat16*)(w + 3432448);   // 1572864 bf16 -> [3432448, 4218880)
    __hip_bfloat16* wfcb = (__hip_bfloat16*)(w + 4218880);   // 4194304 bf16 -> [4218880, 6316032)
    __hip_bfloat16* hnewb= (__hip_bfloat16*)(w + 6316032);   // 8388608 bf16 -> [6316032, 10510336)
    // pre-gru overlays inside hnewb's region (dead before gru writes hnewb):
    float* krow = w + 8413184;                               // [8413184, 8675328)
    __hip_bfloat16* inpb = (__hip_bfloat16*)(w + 8675328);   // 2097152 bf16 -> [8675328, 9723904)
    __hip_bfloat16* WvB  = (__hip_bfloat16*)(w + 9723904);   // 524288 bf16  -> [9723904, 9986048)
    __hip_bfloat16* fcT  = (__hip_bfloat16*)(w + 9986048);   // 1048576 bf16 -> [9986048, 10510336)
    __hip_bfloat16* WvFT = (__hip_bfloat16*)(w + 10510336);  // 524288 bf16  -> [10510336, 10772480)
    // post-gru overlay (Wihb dead):
    __hip_bfloat16* omb  = (__hip_bfloat16*)(w + 286720);    // 2097152 bf16 -> [286720, 1335296)

    // ---- Phase A: conversions / prep ----
    wih_prep<<<dim3(6144), dim3(256), 0, stream>>>(Wih, fc_i_b, bih, Wihb, cbuf);
    f2b3_kernel<<<dim3(4096), dim3(256), 0, stream>>>(
        inp, inpb, Whh, Whhb, Wv_i + 512 * 1024, WvB);
    tconv_kernel<<<dim3(32, 32, 1), dim3(256), 0, stream>>>(fc_i_w, 1024, 0, fcT, 1024, 0);
    tconv_wm<<<dim3(2, 8, 24), dim3(256), 0, stream>>>(Wq_m, Wk_m, Wv_m, WmT);
    fcg_prep<<<dim3(128), dim3(256), 0, stream>>>(fc_m_w, gate_m_w, fcgT);
    // ---- Phase B: mask path (fp32, reordered contraction) + hxb emit ----
    gemm_nn<<<dim3(1, 64, 1), dim3(256), 0, stream>>>(
        inp, Wk_i + 512 * 64, krow, 4096, 64, 512, 512, 64, 64, 0, 0, 0);
    gemm_nt_f32<<<dim3(4, 64, 8), dim3(256), 0, stream>>>(
        krow, 64, Wq_i, 64, pbuf, 2048, 64, 16384, 256);
    s1_mask_fused<<<dim3(1024), dim3(256), 0, stream>>>(hx, pbuf, a_buf, maskb, hxb);
    // WvFT(1024x512) = fcT(1024x1024) @ WvB(512x1024)^T
    gemm_mfma_obf16<<<dim3(8, 8, 1), dim3(256), 0, stream>>>(
        fcT, 1024, WvB, 1024, WvFT, 512, 1024);
    // wfcb(4096x1024) = inpb(4096x512) @ WvFT^T
    gemm_mfma_obf16<<<dim3(16, 32, 1), dim3(256), 0, stream>>>(
        inpb, 512, WvFT, 512, wfcb, 1024, 512);
    // ---- Phase C: fused MFMA GEMM + GRU -> hnewb ----
    gru_fused_mfma<<<dim3(2048), dim3(512), 0, stream>>>(
        wfcb, hxb, a_buf, cbuf, Wihb, Whhb, bhh, hnewb);
    // ---- Phase D: q/k/v_m projections (bf16, into hx_out region) ----
    gemm_mfma_qkv<<<dim3(3, 32, 8), dim3(256), 0, stream>>>(hnewb, WmT, qkvb);
    // ---- Phase E: memory attention + fused att/final ----
    mattn_kernel<<<dim3(512), dim3(256), 0, stream>>>(
        qkvb, qkvb + 2097152, qkvb + 4194304, omb);
    att_final<<<dim3(8, 256, 1), dim3(256), 0, stream>>>(
        omb, fcgT, fc_m_b, gate_m_b, hnewb, maskb, hx, cx, hx_out, cx_out, mask_w);
}